// Round 3
// baseline (603.682 us; speedup 1.0000x reference)
//
#include <hip/hip_runtime.h>
#include <math.h>

#define DT 0.1f
#define EPSL 1e-5f

// ---- output layout (float32, concatenated in reference return order) ----
#define XREC_OFF 0
#define QM_OFF   10035200
#define QV_OFF   10037248
#define ZT_OFF   10039296
#define LH_OFF   10141696
#define KL_OFF   10141697

// ---- workspace layout (bytes) ----
// lhp  float[3200]   @ 0
// klp  float[256]    @ 12800
// z0   float[2048]   @ 13824
// M1p  float[784*12] @ 22016
// Wp2  u32[1600]     @ 59648   (bf16-paired convT2 weights)
// Wc3  float[200]    @ 72448

__device__ __forceinline__ unsigned short f2bf(float x) {
    unsigned int u = __float_as_uint(x);
    u += 0x7fffu + ((u >> 16) & 1u);
    return (unsigned short)(u >> 16);
}
__device__ __forceinline__ float bf2f(unsigned short h) {
    return __uint_as_float(((unsigned int)h) << 16);
}
__device__ __forceinline__ unsigned int pk2(float lo, float hi) {
    return (unsigned int)f2bf(lo) | ((unsigned int)f2bf(hi) << 16);
}
// D = S0.bf16[0]*S1.bf16[0] + S0.bf16[1]*S1.bf16[1] + S2  (exact products, f32 acc)
__device__ __forceinline__ float dot2bfs(unsigned int w, unsigned int y, float c) {
    float d;
    asm("v_dot2_f32_bf16 %0, %1, %2, %3" : "=v"(d) : "s"(w), "v"(y), "v"(c));
    return d;
}

// =====================================================================
// Prep: build M1p + parity-class repacked decoder weights.
// =====================================================================
__global__ __launch_bounds__(256) void prep_kernel(
    const float* __restrict__ fc3w, const float* __restrict__ fc3b,
    const float* __restrict__ dw1, const float* __restrict__ db1,
    const float* __restrict__ dw2, const float* __restrict__ dw3,
    float* __restrict__ M1p, unsigned int* __restrict__ Wp2, float* __restrict__ Wc3)
{
    int idx = blockIdx.x * 256 + threadIdx.x;
    if (idx < 9408) {                       // M1p [784][12]
        int m = idx / 12, j = idx % 12;
        float acc = 0.f;
        if (j < 9) {
            int oc = m / 49, r = m % 49, oy = r / 7, ox = r % 7;
            acc = (j == 8) ? db1[oc] : 0.f;
            for (int ky = 0; ky < 5; ++ky) {
                int ty = oy + ky - 2;
                if (ty < 0 || (ty & 1)) continue;
                int iy = ty >> 1; if (iy >= 4) continue;
                for (int kx = 0; kx < 5; ++kx) {
                    int tx = ox + kx - 2;
                    if (tx < 0 || (tx & 1)) continue;
                    int ix = tx >> 1; if (ix >= 4) continue;
                    for (int ic = 0; ic < 32; ++ic) {
                        float wv = dw1[((oc * 32 + ic) * 5 + ky) * 5 + kx];
                        int mi = ic * 16 + iy * 4 + ix;
                        acc += wv * ((j < 8) ? fc3w[mi * 8 + j] : fc3b[mi]);
                    }
                }
            }
        }
        M1p[idx] = acc;
    } else if (idx < 9408 + 3200) {         // Wp2 repack, dw2 [oc=8][ic=16][ky][kx]
        int iw = idx - 9408;
        int kx = iw % 5, t1 = iw / 5, ky = t1 % 5, t2 = t1 / 5, ic = t2 % 16, oc = t2 / 16;
        int cy = ky & 1, cx = kx & 1, dy = ky >> 1, dx = kx >> 1;
        int ny = cy ? 2 : 3, nx = cx ? 2 : 3, nt = ny * nx;
        const int off2[4] = {0, 576, 960, 1344};   // u32-pair units
        int icp = ic >> 1, half = ic & 1;
        unsigned short* Wp2h = (unsigned short*)Wp2;
        Wp2h[(off2[cy * 2 + cx] + (icp * 8 + oc) * nt + dy * nx + dx) * 2 + half] = f2bf(dw2[iw]);
    } else if (idx < 9408 + 3200 + 200) {   // Wc3 repack (fp32: precision hedge)
        int iw = idx - 12608;
        int kx = iw % 5, t1 = iw / 5, ky = t1 % 5, ic = t1 / 5;
        int cy = ky & 1, cx = kx & 1, dy = ky >> 1, dx = kx >> 1;
        int ny = cy ? 2 : 3, nx = cx ? 2 : 3, nt = ny * nx;
        const int off3[4] = {0, 72, 120, 168};
        Wc3[off3[cy * 2 + cx] + ic * nt + dy * nx + dx] = dw3[iw];
    }
}

// =====================================================================
// Encoder v2 (unchanged): branchless padded convs, LDS weights, parallel fc.
// =====================================================================
__global__ __launch_bounds__(256) void enc_kernel(
    const float* __restrict__ X, const float* __restrict__ eps,
    const float* __restrict__ w1, const float* __restrict__ b1,
    const float* __restrict__ w2, const float* __restrict__ b2,
    const float* __restrict__ w3, const float* __restrict__ b3,
    const float* __restrict__ fc1w, const float* __restrict__ fc1b,
    const float* __restrict__ fc2w, const float* __restrict__ fc2b,
    float* __restrict__ out, float* __restrict__ z0, float* __restrict__ klp)
{
    __shared__ float imgp[33][33];
    __shared__ float a1p[8][17][17];
    __shared__ float a2p[16][11][11];
    __shared__ float h[512];
    __shared__ float w1s[200];
    __shared__ float w2s[3200];
    __shared__ float w3s[12800];
    __shared__ float fcred[16];
    __shared__ float kl_s[8];
    int n = blockIdx.x, tid = threadIdx.x;

    for (int i = tid; i < 1089; i += 256) ((float*)imgp)[i] = 0.f;
    for (int i = tid; i < 2312; i += 256) ((float*)a1p)[i] = 0.f;
    for (int i = tid; i < 1936; i += 256) ((float*)a2p)[i] = 0.f;
    for (int i = tid; i < 50;   i += 256) ((float4*)w1s)[i] = ((const float4*)w1)[i];
    for (int i = tid; i < 800;  i += 256) ((float4*)w2s)[i] = ((const float4*)w2)[i];
    for (int i = tid; i < 3200; i += 256) ((float4*)w3s)[i] = ((const float4*)w3)[i];
    __syncthreads();

    const float* xi = X + (size_t)n * 39200;
    for (int i = tid; i < 784; i += 256) imgp[2 + i / 28][2 + i % 28] = xi[i];
    __syncthreads();

    for (int idx = tid; idx < 1568; idx += 256) {
        int oc = idx / 196, r = idx % 196, oy = r / 14, ox = r % 14;
        float acc = b1[oc];
        const float* wp = w1s + oc * 25;
        #pragma unroll
        for (int ky = 0; ky < 5; ++ky)
            #pragma unroll
            for (int kx = 0; kx < 5; ++kx)
                acc = fmaf(wp[ky * 5 + kx], imgp[2 * oy + ky][2 * ox + kx], acc);
        a1p[oc][2 + oy][2 + ox] = fmaxf(acc, 0.f);
    }
    __syncthreads();

    for (int idx = tid; idx < 784; idx += 256) {
        int oc = idx / 49, r = idx % 49, oy = r / 7, ox = r % 7;
        float acc = b2[oc];
        #pragma unroll 2
        for (int ic = 0; ic < 8; ++ic) {
            const float* wp = w2s + (oc * 8 + ic) * 25;
            #pragma unroll
            for (int ky = 0; ky < 5; ++ky)
                #pragma unroll
                for (int kx = 0; kx < 5; ++kx)
                    acc = fmaf(wp[ky * 5 + kx], a1p[ic][2 * oy + ky][2 * ox + kx], acc);
        }
        a2p[oc][2 + oy][2 + ox] = fmaxf(acc, 0.f);
    }
    __syncthreads();

    for (int idx = tid; idx < 512; idx += 256) {
        int oc = idx / 16, r = idx % 16, oy = r / 4, ox = r % 4;
        float acc = b3[oc];
        #pragma unroll 2
        for (int ic = 0; ic < 16; ++ic) {
            const float* wp = w3s + (oc * 16 + ic) * 25;
            #pragma unroll
            for (int ky = 0; ky < 5; ++ky)
                #pragma unroll
                for (int kx = 0; kx < 5; ++kx)
                    acc = fmaf(wp[ky * 5 + kx], a2p[ic][2 * oy + ky][2 * ox + kx], acc);
        }
        h[oc * 16 + r] = fmaxf(acc, 0.f);
    }
    __syncthreads();

    if (tid < 128) {
        int wv = tid >> 6, L = tid & 63, o = L >> 3, rr = L & 7;
        const float* fw = (wv ? fc2w : fc1w) + o * 512;
        float p = 0.f;
        #pragma unroll 8
        for (int j = 0; j < 64; ++j) {
            int k = rr + 8 * j;
            p = fmaf(fw[k], h[k], p);
        }
        p += __shfl_down(p, 4, 8);
        p += __shfl_down(p, 2, 8);
        p += __shfl_down(p, 1, 8);
        if (rr == 0) fcred[wv * 8 + o] = p;
    }
    __syncthreads();
    if (tid < 8) {
        float m = fc1b[tid] + fcred[tid];
        float lv = fc2b[tid] + fcred[8 + tid];
        float v = fmaxf(lv, 0.f) + log1pf(expf(-fabsf(lv)));
        float z = m + eps[n * 8 + tid] * v;
        out[QM_OFF + n * 8 + tid] = m;
        out[QV_OFF + n * 8 + tid] = v;
        z0[n * 8 + tid] = z;
        kl_s[tid] = -logf(v) + 0.5f * (v * v + m * m) - 0.5f;
    }
    __syncthreads();
    if (tid == 0) {
        float s = 0.f;
        for (int i = 0; i < 8; ++i) s += kl_s[i];
        klp[n] = s;
    }
}

// =====================================================================
// ODE v5: ONE WAVE PER SAMPLE. Zero barriers, zero LDS round-trips.
//  - all weights register-resident: lane L holds W2 rows L and L+64
//    (200 VGPR), W1 rows L/L+64, W3 columns L/L+64. ~290 VGPR total,
//    affordable at __launch_bounds__(64,1) (512-VGPR budget, 1 wave/SIMD).
//  - layer2: readlane broadcast of h1 (intra-wave, in-order, no sync)
//  - layer3: per-lane partials + 6-step shfl_xor butterfly = reduce AND
//    broadcast, so z stays replicated in registers across all lanes.
// =====================================================================
__device__ __forceinline__ float rl(float v, int lane) {
    return __uint_as_float(__builtin_amdgcn_readlane(__float_as_uint(v), lane));
}
__device__ __forceinline__ float wsum64(float v) {
    v += __shfl_xor(v, 1);
    v += __shfl_xor(v, 2);
    v += __shfl_xor(v, 4);
    v += __shfl_xor(v, 8);
    v += __shfl_xor(v, 16);
    v += __shfl_xor(v, 32);
    return v;
}

__global__ __launch_bounds__(64, 1) void ode_kernel(
    const float* __restrict__ z0,
    const float* __restrict__ fw1, const float* __restrict__ fb1,
    const float* __restrict__ fw2, const float* __restrict__ fb2,
    const float* __restrict__ fw3, const float* __restrict__ fb3,
    float* __restrict__ ztg)
{
    int n = blockIdx.x, L = threadIdx.x;
    bool hi = (L < 36);
    int jB = L + 64;   // second hidden unit of this lane (valid when hi)

    float b1a = fb1[L], b2a = fb2[L];
    float b1b = hi ? fb1[jB] : 0.f;
    float b2b = hi ? fb2[jB] : 0.f;

    float w1a[8], w1b[8];
    #pragma unroll
    for (int k = 0; k < 8; ++k) {
        w1a[k] = fw1[L * 8 + k];
        w1b[k] = hi ? fw1[jB * 8 + k] : 0.f;
    }
    float w2a[100], w2b[100];
    #pragma unroll
    for (int k = 0; k < 100; ++k) {
        w2a[k] = fw2[L * 100 + k];
        w2b[k] = hi ? fw2[jB * 100 + k] : 0.f;
    }
    float w3a[8], w3b[8], b3v[8];
    #pragma unroll
    for (int j = 0; j < 8; ++j) {
        w3a[j] = fw3[j * 100 + L];
        w3b[j] = hi ? fw3[j * 100 + jB] : 0.f;
        b3v[j] = fb3[j];
    }

    float zc[8];
    #pragma unroll
    for (int j = 0; j < 8; ++j) zc[j] = z0[n * 8 + j];
    if (L == 0) {
        *(float4*)&ztg[n * 400]     = float4{zc[0], zc[1], zc[2], zc[3]};
        *(float4*)&ztg[n * 400 + 4] = float4{zc[4], zc[5], zc[6], zc[7]};
    }

    #pragma unroll 1
    for (int t = 1; t < 50; ++t) {
        float zs[8], zin[8];
        #pragma unroll
        for (int j = 0; j < 8; ++j) { zs[j] = 0.f; zin[j] = zc[j]; }
        #pragma unroll
        for (int st = 0; st < 4; ++st) {
            // layer1: local (z replicated in every lane)
            float aa = b1a, ab = b1b;
            #pragma unroll
            for (int k = 0; k < 8; ++k) {
                aa = fmaf(w1a[k], zin[k], aa);
                ab = fmaf(w1b[k], zin[k], ab);
            }
            aa = fmaxf(aa, 0.f);
            ab = fmaxf(ab, 0.f);

            // layer2: broadcast h1 lane-by-lane, accumulate own rows
            float pa[4] = {b2a, 0.f, 0.f, 0.f};
            float pb[4] = {b2b, 0.f, 0.f, 0.f};
            #pragma unroll
            for (int kk = 0; kk < 64; ++kk) {
                float s = rl(aa, kk);
                pa[kk & 3] = fmaf(w2a[kk], s, pa[kk & 3]);
                pb[kk & 3] = fmaf(w2b[kk], s, pb[kk & 3]);
            }
            #pragma unroll
            for (int kk = 0; kk < 36; ++kk) {
                float s = rl(ab, kk);
                pa[kk & 3] = fmaf(w2a[64 + kk], s, pa[kk & 3]);
                pb[kk & 3] = fmaf(w2b[64 + kk], s, pb[kk & 3]);
            }
            float h2a = fmaxf((pa[0] + pa[1]) + (pa[2] + pa[3]), 0.f);
            float h2b = fmaxf((pb[0] + pb[1]) + (pb[2] + pb[3]), 0.f);

            // layer3: per-lane partials + butterfly (reduce + broadcast)
            float po[8];
            #pragma unroll
            for (int j = 0; j < 8; ++j)
                po[j] = fmaf(w3a[j], h2a, w3b[j] * h2b);
            #pragma unroll
            for (int j = 0; j < 8; ++j)
                po[j] = wsum64(po[j]);

            float cw = (st == 0 || st == 3) ? (DT / 6.f) : (DT / 3.f);
            if (st < 3) {
                float cin = (st == 2) ? DT : 0.5f * DT;
                #pragma unroll
                for (int j = 0; j < 8; ++j) {
                    float o = po[j] + b3v[j];
                    zs[j] = fmaf(cw, o, zs[j]);
                    zin[j] = fmaf(cin, o, zc[j]);
                }
            } else {
                #pragma unroll
                for (int j = 0; j < 8; ++j) {
                    float o = po[j] + b3v[j];
                    zc[j] = zc[j] + fmaf(cw, o, zs[j]);
                }
                if (L == 0) {
                    *(float4*)&ztg[n * 400 + t * 8]     = float4{zc[0], zc[1], zc[2], zc[3]};
                    *(float4*)&ztg[n * 400 + t * 8 + 4] = float4{zc[4], zc[5], zc[6], zc[7]};
                }
            }
        }
    }
}

// =====================================================================
// Decoder v9.1: v9 + y1p padded to stride 11 (bank-conflict trim).
// =====================================================================
__global__ __launch_bounds__(256, 5) void dec_kernel(
    const float* __restrict__ M1p, const float* __restrict__ zt,
    const unsigned int* __restrict__ Wp2, const float* __restrict__ db2,
    const float* __restrict__ Wc3, const float* __restrict__ db3,
    const float* __restrict__ X, float* __restrict__ xrec,
    float* __restrict__ lhp)
{
    __shared__ __align__(16) unsigned int y1p[4][8][9][11];    // bf16 ic-pairs, 12672 B
    __shared__ __align__(16) unsigned int y2p[4][4][16][17];   // bf16 ic-pairs, 17408 B
    __shared__ float red4[4];
    int blk = blockIdx.x, tid = threadIdx.x;
    int wv = tid >> 6, L = tid & 63;

    {
        uint4 z4 = uint4{0u, 0u, 0u, 0u};
        for (int i = tid; i < 792;  i += 256) ((uint4*)y1p)[i] = z4;
        for (int i = tid; i < 1088; i += 256) ((uint4*)y2p)[i] = z4;
    }
    __syncthreads();

    // phase 0: y1 = relu(M1 @ z + b), two channels (one pair) per work item
    {
        float zr[4][8];
        const float* zp = zt + (size_t)blk * 32;
        #pragma unroll
        for (int s = 0; s < 4; ++s)
            #pragma unroll
            for (int jj = 0; jj < 8; ++jj) zr[s][jj] = zp[s * 8 + jj];
        for (int m2 = tid; m2 < 392; m2 += 256) {
            int icp = m2 / 49, r = m2 % 49, oy = r / 7, ox = r % 7;
            const float4* rowA = (const float4*)(M1p + (size_t)((icp * 2) * 49 + r) * 12);
            const float4* rowB = (const float4*)(M1p + (size_t)((icp * 2 + 1) * 49 + r) * 12);
            float4 a0 = rowA[0], a1 = rowA[1], a2 = rowA[2];
            float4 b0 = rowB[0], b1 = rowB[1], b2 = rowB[2];
            #pragma unroll
            for (int s = 0; s < 4; ++s) {
                float aA = a2.x
                    + a0.x * zr[s][0] + a0.y * zr[s][1] + a0.z * zr[s][2] + a0.w * zr[s][3]
                    + a1.x * zr[s][4] + a1.y * zr[s][5] + a1.z * zr[s][6] + a1.w * zr[s][7];
                float aB = b2.x
                    + b0.x * zr[s][0] + b0.y * zr[s][1] + b0.z * zr[s][2] + b0.w * zr[s][3]
                    + b1.x * zr[s][4] + b1.y * zr[s][5] + b1.z * zr[s][6] + b1.w * zr[s][7];
                y1p[s][icp][1 + oy][1 + ox] = pk2(fmaxf(aA, 0.f), fmaxf(aB, 0.f));
            }
        }
    }
    __syncthreads();

    // phase 1: convT2 fused 4-class 2x2 tiles via v_dot2_f32_bf16.
    {
        int pos = (L < 49) ? L : 48;
        int s = wv, m = pos / 7, n = pos % 7;
        float acc[4][8];
        #pragma unroll
        for (int oc = 0; oc < 8; ++oc) {
            float b = db2[oc];
            acc[0][oc] = b; acc[1][oc] = b; acc[2][oc] = b; acc[3][oc] = b;
        }
        #pragma unroll 2
        for (int icp = 0; icp < 8; ++icp) {
            unsigned int yv[3][3];
            #pragma unroll
            for (int ry = 0; ry < 3; ++ry)
                #pragma unroll
                for (int rx = 0; rx < 3; ++rx)
                    yv[ry][rx] = y1p[s][icp][m + ry][n + rx];
            #pragma unroll
            for (int oc = 0; oc < 8; ++oc) {
                const unsigned int* p00 = Wp2 + (icp * 8 + oc) * 9;
                const unsigned int* p01 = Wp2 + 576 + (icp * 8 + oc) * 6;
                const unsigned int* p10 = Wp2 + 960 + (icp * 8 + oc) * 6;
                const unsigned int* p11 = Wp2 + 1344 + (icp * 8 + oc) * 4;
                #pragma unroll
                for (int dy = 0; dy < 3; ++dy)
                    #pragma unroll
                    for (int dx = 0; dx < 3; ++dx)
                        acc[0][oc] = dot2bfs(p00[dy * 3 + dx], yv[dy][dx], acc[0][oc]);
                #pragma unroll
                for (int dy = 0; dy < 3; ++dy)
                    #pragma unroll
                    for (int dx = 0; dx < 2; ++dx)
                        acc[1][oc] = dot2bfs(p01[dy * 2 + dx], yv[dy][dx + 1], acc[1][oc]);
                #pragma unroll
                for (int dy = 0; dy < 2; ++dy)
                    #pragma unroll
                    for (int dx = 0; dx < 3; ++dx)
                        acc[2][oc] = dot2bfs(p10[dy * 3 + dx], yv[dy + 1][dx], acc[2][oc]);
                #pragma unroll
                for (int dy = 0; dy < 2; ++dy)
                    #pragma unroll
                    for (int dx = 0; dx < 2; ++dx)
                        acc[3][oc] = dot2bfs(p11[dy * 2 + dx], yv[dy + 1][dx + 1], acc[3][oc]);
            }
        }
        if (L < 49) {
            #pragma unroll
            for (int p = 0; p < 4; ++p) {
                y2p[s][p][1 + 2 * m][1 + 2 * n] = pk2(fmaxf(acc[0][2 * p], 0.f), fmaxf(acc[0][2 * p + 1], 0.f));
                y2p[s][p][1 + 2 * m][2 + 2 * n] = pk2(fmaxf(acc[1][2 * p], 0.f), fmaxf(acc[1][2 * p + 1], 0.f));
                y2p[s][p][2 + 2 * m][1 + 2 * n] = pk2(fmaxf(acc[2][2 * p], 0.f), fmaxf(acc[2][2 * p + 1], 0.f));
                y2p[s][p][2 + 2 * m][2 + 2 * n] = pk2(fmaxf(acc[3][2 * p], 0.f), fmaxf(acc[3][2 * p + 1], 0.f));
            }
        }
    }
    __syncthreads();

    // phase 2: convT3 fused 4-class 2x2 tiles + sigmoid + lhood (fp32 weights)
    float part = 0.f;
    {
        float b3v = db3[0];
        const float* q00 = Wc3;
        const float* q01 = Wc3 + 72;
        const float* q10 = Wc3 + 120;
        const float* q11 = Wc3 + 168;
        #pragma unroll 1
        for (int ch = 0; ch < 4; ++ch) {
            int g = ch * 256 + tid;
            if (g < 784) {
                int s2 = g / 196, r2 = g % 196, m = r2 / 14, n = r2 % 14;
                float o00 = b3v, o01 = b3v, o10 = b3v, o11 = b3v;
                #pragma unroll
                for (int icp = 0; icp < 4; ++icp) {
                    float ylo[3][3], yhi[3][3];
                    #pragma unroll
                    for (int ry = 0; ry < 3; ++ry)
                        #pragma unroll
                        for (int rx = 0; rx < 3; ++rx) {
                            unsigned int u = y2p[s2][icp][m + ry][n + rx];
                            ylo[ry][rx] = __uint_as_float(u << 16);
                            yhi[ry][rx] = __uint_as_float(u & 0xffff0000u);
                        }
                    int ic0 = 2 * icp, ic1 = 2 * icp + 1;
                    #pragma unroll
                    for (int dy = 0; dy < 3; ++dy)
                        #pragma unroll
                        for (int dx = 0; dx < 3; ++dx) {
                            o00 = fmaf(q00[ic0 * 9 + dy * 3 + dx], ylo[dy][dx], o00);
                            o00 = fmaf(q00[ic1 * 9 + dy * 3 + dx], yhi[dy][dx], o00);
                        }
                    #pragma unroll
                    for (int dy = 0; dy < 3; ++dy)
                        #pragma unroll
                        for (int dx = 0; dx < 2; ++dx) {
                            o01 = fmaf(q01[ic0 * 6 + dy * 2 + dx], ylo[dy][dx + 1], o01);
                            o01 = fmaf(q01[ic1 * 6 + dy * 2 + dx], yhi[dy][dx + 1], o01);
                        }
                    #pragma unroll
                    for (int dy = 0; dy < 2; ++dy)
                        #pragma unroll
                        for (int dx = 0; dx < 3; ++dx) {
                            o10 = fmaf(q10[ic0 * 6 + dy * 3 + dx], ylo[dy + 1][dx], o10);
                            o10 = fmaf(q10[ic1 * 6 + dy * 3 + dx], yhi[dy + 1][dx], o10);
                        }
                    #pragma unroll
                    for (int dy = 0; dy < 2; ++dy)
                        #pragma unroll
                        for (int dx = 0; dx < 2; ++dx) {
                            o11 = fmaf(q11[ic0 * 4 + dy * 2 + dx], ylo[dy + 1][dx + 1], o11);
                            o11 = fmaf(q11[ic1 * 4 + dy * 2 + dx], yhi[dy + 1][dx + 1], o11);
                        }
                }
                float p00s = 1.f / (1.f + __expf(-o00));
                float p01s = 1.f / (1.f + __expf(-o01));
                float p10s = 1.f / (1.f + __expf(-o10));
                float p11s = 1.f / (1.f + __expf(-o11));
                size_t base = (size_t)blk * 3136 + s2 * 784 + 2 * m * 28 + 2 * n;
                *(float2*)(xrec + base)      = float2{p00s, p01s};
                *(float2*)(xrec + base + 28) = float2{p10s, p11s};
                float2 x0 = *(const float2*)(X + base);
                float2 x1 = *(const float2*)(X + base + 28);
                part += __logf(EPSL + p00s) * x0.x + __logf(EPSL + 1.f - p00s) * (1.f - x0.x);
                part += __logf(EPSL + p01s) * x0.y + __logf(EPSL + 1.f - p01s) * (1.f - x0.y);
                part += __logf(EPSL + p10s) * x1.x + __logf(EPSL + 1.f - p10s) * (1.f - x1.x);
                part += __logf(EPSL + p11s) * x1.y + __logf(EPSL + 1.f - p11s) * (1.f - x1.y);
            }
        }
    }
    // per-wave shuffle reduce, then one cross-wave combine
    part += __shfl_down(part, 32);
    part += __shfl_down(part, 16);
    part += __shfl_down(part, 8);
    part += __shfl_down(part, 4);
    part += __shfl_down(part, 2);
    part += __shfl_down(part, 1);
    if (L == 0) red4[wv] = part;
    __syncthreads();
    if (tid == 0) lhp[blk] = (red4[0] + red4[1]) + (red4[2] + red4[3]);
}

// =====================================================================
// Finalize
// =====================================================================
__global__ __launch_bounds__(256) void fin_kernel(
    const float* __restrict__ lhp, const float* __restrict__ klp,
    float* __restrict__ out)
{
    __shared__ double red[256];
    int tid = threadIdx.x;
    double s = 0.0;
    for (int i = tid; i < 3200; i += 256) s += (double)lhp[i];
    red[tid] = s;
    __syncthreads();
    for (int st = 128; st > 0; st >>= 1) {
        if (tid < st) red[tid] += red[tid + st];
        __syncthreads();
    }
    double lh = red[0];
    __syncthreads();
    red[tid] = (double)klp[tid];
    __syncthreads();
    for (int st = 128; st > 0; st >>= 1) {
        if (tid < st) red[tid] += red[tid + st];
        __syncthreads();
    }
    if (tid == 0) {
        out[LH_OFF] = (float)(lh / 256.0);
        out[KL_OFF] = (float)(red[0] / 2048.0);
    }
}

extern "C" void kernel_launch(void* const* d_in, const int* in_sizes, int n_in,
                              void* d_out, int out_size, void* d_ws, size_t ws_size,
                              hipStream_t stream) {
    const float* X     = (const float*)d_in[0];
    const float* eps   = (const float*)d_in[1];
    const float* ew1   = (const float*)d_in[2];
    const float* eb1   = (const float*)d_in[3];
    const float* ew2   = (const float*)d_in[4];
    const float* eb2   = (const float*)d_in[5];
    const float* ew3   = (const float*)d_in[6];
    const float* eb3   = (const float*)d_in[7];
    const float* fc1w  = (const float*)d_in[8];
    const float* fc1b  = (const float*)d_in[9];
    const float* fc2w  = (const float*)d_in[10];
    const float* fc2b  = (const float*)d_in[11];
    const float* fw1   = (const float*)d_in[12];
    const float* fb1   = (const float*)d_in[13];
    const float* fw2   = (const float*)d_in[14];
    const float* fb2   = (const float*)d_in[15];
    const float* fw3   = (const float*)d_in[16];
    const float* fb3   = (const float*)d_in[17];
    const float* fc3w  = (const float*)d_in[18];
    const float* fc3b  = (const float*)d_in[19];
    const float* dw1   = (const float*)d_in[20];
    const float* db1   = (const float*)d_in[21];
    const float* dw2   = (const float*)d_in[22];
    const float* db2   = (const float*)d_in[23];
    const float* dw3   = (const float*)d_in[24];
    const float* db3   = (const float*)d_in[25];

    float* out = (float*)d_out;
    char* ws = (char*)d_ws;
    float* lhp = (float*)ws;
    float* klp = (float*)(ws + 12800);
    float* z0  = (float*)(ws + 13824);
    float* M1p = (float*)(ws + 22016);
    unsigned int* Wp2 = (unsigned int*)(ws + 59648);
    float* Wc3 = (float*)(ws + 72448);

    prep_kernel<<<51, 256, 0, stream>>>(fc3w, fc3b, dw1, db1, dw2, dw3, M1p, Wp2, Wc3);
    enc_kernel<<<256, 256, 0, stream>>>(X, eps, ew1, eb1, ew2, eb2, ew3, eb3,
                                        fc1w, fc1b, fc2w, fc2b, out, z0, klp);
    ode_kernel<<<256, 64, 0, stream>>>(z0, fw1, fb1, fw2, fb2, fw3, fb3, out + ZT_OFF);
    dec_kernel<<<3200, 256, 0, stream>>>(M1p, out + ZT_OFF, Wp2, db2, Wc3, db3,
                                         X, out + XREC_OFF, lhp);
    fin_kernel<<<1, 256, 0, stream>>>(lhp, klp, out);
}

// Round 5
// 474.925 us; speedup vs baseline: 1.2711x; 1.2711x over previous
//
#include <hip/hip_runtime.h>
#include <math.h>

#define DT 0.1f
#define EPSL 1e-5f

// ---- output layout (float32, concatenated in reference return order) ----
#define XREC_OFF 0
#define QM_OFF   10035200
#define QV_OFF   10037248
#define ZT_OFF   10039296
#define LH_OFF   10141696
#define KL_OFF   10141697

// ---- workspace layout (bytes) ----
// lhp  float[3200]   @ 0
// klp  float[256]    @ 12800
// z0   float[2048]   @ 13824
// M1p  float[784*12] @ 22016
// Wp2  u32[1600]     @ 59648   (bf16-paired convT2 weights)
// Wc3  float[200]    @ 72448

__device__ __forceinline__ unsigned short f2bf(float x) {
    unsigned int u = __float_as_uint(x);
    u += 0x7fffu + ((u >> 16) & 1u);
    return (unsigned short)(u >> 16);
}
__device__ __forceinline__ float bf2f(unsigned short h) {
    return __uint_as_float(((unsigned int)h) << 16);
}
__device__ __forceinline__ unsigned int pk2(float lo, float hi) {
    return (unsigned int)f2bf(lo) | ((unsigned int)f2bf(hi) << 16);
}
// D = S0.bf16[0]*S1.bf16[0] + S0.bf16[1]*S1.bf16[1] + S2  (exact products, f32 acc)
__device__ __forceinline__ float dot2bfs(unsigned int w, unsigned int y, float c) {
    float d;
    asm("v_dot2_f32_bf16 %0, %1, %2, %3" : "=v"(d) : "s"(w), "v"(y), "v"(c));
    return d;
}

// =====================================================================
// Prep: build M1p + parity-class repacked decoder weights.
// =====================================================================
__global__ __launch_bounds__(256) void prep_kernel(
    const float* __restrict__ fc3w, const float* __restrict__ fc3b,
    const float* __restrict__ dw1, const float* __restrict__ db1,
    const float* __restrict__ dw2, const float* __restrict__ dw3,
    float* __restrict__ M1p, unsigned int* __restrict__ Wp2, float* __restrict__ Wc3)
{
    int idx = blockIdx.x * 256 + threadIdx.x;
    if (idx < 9408) {                       // M1p [784][12]
        int m = idx / 12, j = idx % 12;
        float acc = 0.f;
        if (j < 9) {
            int oc = m / 49, r = m % 49, oy = r / 7, ox = r % 7;
            acc = (j == 8) ? db1[oc] : 0.f;
            for (int ky = 0; ky < 5; ++ky) {
                int ty = oy + ky - 2;
                if (ty < 0 || (ty & 1)) continue;
                int iy = ty >> 1; if (iy >= 4) continue;
                for (int kx = 0; kx < 5; ++kx) {
                    int tx = ox + kx - 2;
                    if (tx < 0 || (tx & 1)) continue;
                    int ix = tx >> 1; if (ix >= 4) continue;
                    for (int ic = 0; ic < 32; ++ic) {
                        float wv = dw1[((oc * 32 + ic) * 5 + ky) * 5 + kx];
                        int mi = ic * 16 + iy * 4 + ix;
                        acc += wv * ((j < 8) ? fc3w[mi * 8 + j] : fc3b[mi]);
                    }
                }
            }
        }
        M1p[idx] = acc;
    } else if (idx < 9408 + 3200) {         // Wp2 repack, dw2 [oc=8][ic=16][ky][kx]
        int iw = idx - 9408;
        int kx = iw % 5, t1 = iw / 5, ky = t1 % 5, t2 = t1 / 5, ic = t2 % 16, oc = t2 / 16;
        int cy = ky & 1, cx = kx & 1, dy = ky >> 1, dx = kx >> 1;
        int ny = cy ? 2 : 3, nx = cx ? 2 : 3, nt = ny * nx;
        const int off2[4] = {0, 576, 960, 1344};   // u32-pair units
        int icp = ic >> 1, half = ic & 1;
        unsigned short* Wp2h = (unsigned short*)Wp2;
        Wp2h[(off2[cy * 2 + cx] + (icp * 8 + oc) * nt + dy * nx + dx) * 2 + half] = f2bf(dw2[iw]);
    } else if (idx < 9408 + 3200 + 200) {   // Wc3 repack (fp32: precision hedge)
        int iw = idx - 12608;
        int kx = iw % 5, t1 = iw / 5, ky = t1 % 5, ic = t1 / 5;
        int cy = ky & 1, cx = kx & 1, dy = ky >> 1, dx = kx >> 1;
        int ny = cy ? 2 : 3, nx = cx ? 2 : 3, nt = ny * nx;
        const int off3[4] = {0, 72, 120, 168};
        Wc3[off3[cy * 2 + cx] + ic * nt + dy * nx + dx] = dw3[iw];
    }
}

// =====================================================================
// Encoder v2 (unchanged): branchless padded convs, LDS weights, parallel fc.
// =====================================================================
__global__ __launch_bounds__(256) void enc_kernel(
    const float* __restrict__ X, const float* __restrict__ eps,
    const float* __restrict__ w1, const float* __restrict__ b1,
    const float* __restrict__ w2, const float* __restrict__ b2,
    const float* __restrict__ w3, const float* __restrict__ b3,
    const float* __restrict__ fc1w, const float* __restrict__ fc1b,
    const float* __restrict__ fc2w, const float* __restrict__ fc2b,
    float* __restrict__ out, float* __restrict__ z0, float* __restrict__ klp)
{
    __shared__ float imgp[33][33];
    __shared__ float a1p[8][17][17];
    __shared__ float a2p[16][11][11];
    __shared__ float h[512];
    __shared__ float w1s[200];
    __shared__ float w2s[3200];
    __shared__ float w3s[12800];
    __shared__ float fcred[16];
    __shared__ float kl_s[8];
    int n = blockIdx.x, tid = threadIdx.x;

    for (int i = tid; i < 1089; i += 256) ((float*)imgp)[i] = 0.f;
    for (int i = tid; i < 2312; i += 256) ((float*)a1p)[i] = 0.f;
    for (int i = tid; i < 1936; i += 256) ((float*)a2p)[i] = 0.f;
    for (int i = tid; i < 50;   i += 256) ((float4*)w1s)[i] = ((const float4*)w1)[i];
    for (int i = tid; i < 800;  i += 256) ((float4*)w2s)[i] = ((const float4*)w2)[i];
    for (int i = tid; i < 3200; i += 256) ((float4*)w3s)[i] = ((const float4*)w3)[i];
    __syncthreads();

    const float* xi = X + (size_t)n * 39200;
    for (int i = tid; i < 784; i += 256) imgp[2 + i / 28][2 + i % 28] = xi[i];
    __syncthreads();

    for (int idx = tid; idx < 1568; idx += 256) {
        int oc = idx / 196, r = idx % 196, oy = r / 14, ox = r % 14;
        float acc = b1[oc];
        const float* wp = w1s + oc * 25;
        #pragma unroll
        for (int ky = 0; ky < 5; ++ky)
            #pragma unroll
            for (int kx = 0; kx < 5; ++kx)
                acc = fmaf(wp[ky * 5 + kx], imgp[2 * oy + ky][2 * ox + kx], acc);
        a1p[oc][2 + oy][2 + ox] = fmaxf(acc, 0.f);
    }
    __syncthreads();

    for (int idx = tid; idx < 784; idx += 256) {
        int oc = idx / 49, r = idx % 49, oy = r / 7, ox = r % 7;
        float acc = b2[oc];
        #pragma unroll 2
        for (int ic = 0; ic < 8; ++ic) {
            const float* wp = w2s + (oc * 8 + ic) * 25;
            #pragma unroll
            for (int ky = 0; ky < 5; ++ky)
                #pragma unroll
                for (int kx = 0; kx < 5; ++kx)
                    acc = fmaf(wp[ky * 5 + kx], a1p[ic][2 * oy + ky][2 * ox + kx], acc);
        }
        a2p[oc][2 + oy][2 + ox] = fmaxf(acc, 0.f);
    }
    __syncthreads();

    for (int idx = tid; idx < 512; idx += 256) {
        int oc = idx / 16, r = idx % 16, oy = r / 4, ox = r % 4;
        float acc = b3[oc];
        #pragma unroll 2
        for (int ic = 0; ic < 16; ++ic) {
            const float* wp = w3s + (oc * 16 + ic) * 25;
            #pragma unroll
            for (int ky = 0; ky < 5; ++ky)
                #pragma unroll
                for (int kx = 0; kx < 5; ++kx)
                    acc = fmaf(wp[ky * 5 + kx], a2p[ic][2 * oy + ky][2 * ox + kx], acc);
        }
        h[oc * 16 + r] = fmaxf(acc, 0.f);
    }
    __syncthreads();

    if (tid < 128) {
        int wv = tid >> 6, L = tid & 63, o = L >> 3, rr = L & 7;
        const float* fw = (wv ? fc2w : fc1w) + o * 512;
        float p = 0.f;
        #pragma unroll 8
        for (int j = 0; j < 64; ++j) {
            int k = rr + 8 * j;
            p = fmaf(fw[k], h[k], p);
        }
        p += __shfl_down(p, 4, 8);
        p += __shfl_down(p, 2, 8);
        p += __shfl_down(p, 1, 8);
        if (rr == 0) fcred[wv * 8 + o] = p;
    }
    __syncthreads();
    if (tid < 8) {
        float m = fc1b[tid] + fcred[tid];
        float lv = fc2b[tid] + fcred[8 + tid];
        float v = fmaxf(lv, 0.f) + log1pf(expf(-fabsf(lv)));
        float z = m + eps[n * 8 + tid] * v;
        out[QM_OFF + n * 8 + tid] = m;
        out[QV_OFF + n * 8 + tid] = v;
        z0[n * 8 + tid] = z;
        kl_s[tid] = -logf(v) + 0.5f * (v * v + m * m) - 0.5f;
    }
    __syncthreads();
    if (tid == 0) {
        float s = 0.f;
        for (int i = 0; i < 8; ++i) s += kl_s[i];
        klp[n] = s;
    }
}

// =====================================================================
// ODE v6.1: 4 waves/sample, ONE barrier per RK4 sub-stage.
// (v6 with the DPP ctrl made a template parameter — compile fix.)
// =====================================================================
__device__ __forceinline__ float rl(float v, int lane) {
    return __uint_as_float(__builtin_amdgcn_readlane(__float_as_uint(v), lane));
}
template<int CTRL>
__device__ __forceinline__ float dppadd(float x) {
    int t = __builtin_amdgcn_update_dpp(0, __float_as_int(x), CTRL, 0xf, 0xf, true);
    return x + __int_as_float(t);
}
// full 64-lane sum, result in lane 63
__device__ __forceinline__ float wsum_dpp(float x) {
    x = dppadd<0x111>(x);   // row_shr:1
    x = dppadd<0x112>(x);   // row_shr:2
    x = dppadd<0x114>(x);   // row_shr:4
    x = dppadd<0x118>(x);   // row_shr:8
    x = dppadd<0x142>(x);   // row_bcast15
    x = dppadd<0x143>(x);   // row_bcast31
    return x;
}

__global__ __launch_bounds__(256, 1) void ode_kernel(
    const float* __restrict__ z0,
    const float* __restrict__ fw1, const float* __restrict__ fb1,
    const float* __restrict__ fw2, const float* __restrict__ fb2,
    const float* __restrict__ fw3, const float* __restrict__ fb3,
    float* __restrict__ ztg)
{
    __shared__ float part2[2][4][128];
    int n = blockIdx.x, tid = threadIdx.x;
    int w = tid >> 6, L = tid & 63;
    bool hi = (L < 36);
    int rB = L + 64;

    // layer1 rows L, L+64 (replicated across waves)
    float b1a = fb1[L];
    float b1b = hi ? fb1[rB] : 0.f;
    float w1a[8], w1b[8];
    #pragma unroll
    for (int k = 0; k < 8; ++k) {
        w1a[k] = fw1[L * 8 + k];
        w1b[k] = hi ? fw1[rB * 8 + k] : 0.f;
    }
    // layer2 rows L, L+64, k-chunk {w, w+4, ..., w+96} (25 ks)
    float b2a = fb2[L];
    float b2b = hi ? fb2[rB] : 0.f;
    float w2a[25], w2b[25];
    #pragma unroll
    for (int kk = 0; kk < 25; ++kk) {
        int k = 4 * kk + w;
        w2a[kk] = fw2[L * 100 + k];
        w2b[kk] = hi ? fw2[rB * 100 + k] : 0.f;
    }
    // layer3 columns L, L+64 (replicated across waves)
    float w3a[8], w3b[8], b3v[8];
    #pragma unroll
    for (int j = 0; j < 8; ++j) {
        w3a[j] = fw3[j * 100 + L];
        w3b[j] = hi ? fw3[j * 100 + rB] : 0.f;
        b3v[j] = fb3[j];
    }

    float zc[8];
    #pragma unroll
    for (int j = 0; j < 8; ++j) zc[j] = z0[n * 8 + j];
    if (tid == 0) {
        *(float4*)&ztg[n * 400]     = float4{zc[0], zc[1], zc[2], zc[3]};
        *(float4*)&ztg[n * 400 + 4] = float4{zc[4], zc[5], zc[6], zc[7]};
    }

    int buf = 0;
    #pragma unroll 1
    for (int t = 1; t < 50; ++t) {
        float zs[8], zin[8];
        #pragma unroll
        for (int j = 0; j < 8; ++j) { zs[j] = 0.f; zin[j] = zc[j]; }
        #pragma unroll 1
        for (int st = 0; st < 4; ++st) {
            // layer1: full h1 rows L / L+64, every wave
            float aa = b1a, ab = b1b;
            #pragma unroll
            for (int k = 0; k < 8; ++k) {
                aa = fmaf(w1a[k], zin[k], aa);
                ab = fmaf(w1b[k], zin[k], ab);
            }
            aa = fmaxf(aa, 0.f);
            ab = fmaxf(ab, 0.f);

            // layer2: this wave's k-chunk; h1[k] via readlane broadcast
            float pa[4] = {0.f, 0.f, 0.f, 0.f};
            float pb[4] = {0.f, 0.f, 0.f, 0.f};
            #pragma unroll
            for (int kk = 0; kk < 16; ++kk) {          // k = 4kk+w < 64 -> aa
                float s = rl(aa, 4 * kk + w);
                pa[kk & 3] = fmaf(w2a[kk], s, pa[kk & 3]);
                pb[kk & 3] = fmaf(w2b[kk], s, pb[kk & 3]);
            }
            #pragma unroll
            for (int kk = 16; kk < 25; ++kk) {         // k >= 64 -> ab lane k-64
                float s = rl(ab, 4 * (kk - 16) + w);
                pa[kk & 3] = fmaf(w2a[kk], s, pa[kk & 3]);
                pb[kk & 3] = fmaf(w2b[kk], s, pb[kk & 3]);
            }
            part2[buf][w][L] = (pa[0] + pa[1]) + (pa[2] + pa[3]);
            if (hi) part2[buf][w][64 + L] = (pb[0] + pb[1]) + (pb[2] + pb[3]);
            __syncthreads();

            // h2 rows L / L+64, every wave (identical values)
            float h2a = fmaxf(b2a + ((part2[buf][0][L] + part2[buf][1][L])
                                   + (part2[buf][2][L] + part2[buf][3][L])), 0.f);
            float h2b = 0.f;
            if (hi)
                h2b = fmaxf(b2b + ((part2[buf][0][64 + L] + part2[buf][1][64 + L])
                                 + (part2[buf][2][64 + L] + part2[buf][3][64 + L])), 0.f);
            buf ^= 1;

            // layer3: per-lane partials + DPP wave-sum (replicated result)
            float o[8];
            #pragma unroll
            for (int j = 0; j < 8; ++j) {
                float po = fmaf(w3a[j], h2a, w3b[j] * h2b);
                o[j] = rl(wsum_dpp(po), 63) + b3v[j];
            }

            float cw = (st == 0 || st == 3) ? (DT / 6.f) : (DT / 3.f);
            if (st < 3) {
                float cin = (st == 2) ? DT : 0.5f * DT;
                #pragma unroll
                for (int j = 0; j < 8; ++j) {
                    zs[j] = fmaf(cw, o[j], zs[j]);
                    zin[j] = fmaf(cin, o[j], zc[j]);
                }
            } else {
                #pragma unroll
                for (int j = 0; j < 8; ++j)
                    zc[j] = zc[j] + fmaf(cw, o[j], zs[j]);
                if (tid == 0) {
                    *(float4*)&ztg[n * 400 + t * 8]     = float4{zc[0], zc[1], zc[2], zc[3]};
                    *(float4*)&ztg[n * 400 + t * 8 + 4] = float4{zc[4], zc[5], zc[6], zc[7]};
                }
            }
        }
    }
}

// =====================================================================
// Decoder v9.1 (unchanged): dot2 phase 1, padded y1p.
// =====================================================================
__global__ __launch_bounds__(256, 5) void dec_kernel(
    const float* __restrict__ M1p, const float* __restrict__ zt,
    const unsigned int* __restrict__ Wp2, const float* __restrict__ db2,
    const float* __restrict__ Wc3, const float* __restrict__ db3,
    const float* __restrict__ X, float* __restrict__ xrec,
    float* __restrict__ lhp)
{
    __shared__ __align__(16) unsigned int y1p[4][8][9][11];    // bf16 ic-pairs, 12672 B
    __shared__ __align__(16) unsigned int y2p[4][4][16][17];   // bf16 ic-pairs, 17408 B
    __shared__ float red4[4];
    int blk = blockIdx.x, tid = threadIdx.x;
    int wv = tid >> 6, L = tid & 63;

    {
        uint4 z4 = uint4{0u, 0u, 0u, 0u};
        for (int i = tid; i < 792;  i += 256) ((uint4*)y1p)[i] = z4;
        for (int i = tid; i < 1088; i += 256) ((uint4*)y2p)[i] = z4;
    }
    __syncthreads();

    // phase 0: y1 = relu(M1 @ z + b), two channels (one pair) per work item
    {
        float zr[4][8];
        const float* zp = zt + (size_t)blk * 32;
        #pragma unroll
        for (int s = 0; s < 4; ++s)
            #pragma unroll
            for (int jj = 0; jj < 8; ++jj) zr[s][jj] = zp[s * 8 + jj];
        for (int m2 = tid; m2 < 392; m2 += 256) {
            int icp = m2 / 49, r = m2 % 49, oy = r / 7, ox = r % 7;
            const float4* rowA = (const float4*)(M1p + (size_t)((icp * 2) * 49 + r) * 12);
            const float4* rowB = (const float4*)(M1p + (size_t)((icp * 2 + 1) * 49 + r) * 12);
            float4 a0 = rowA[0], a1 = rowA[1], a2 = rowA[2];
            float4 b0 = rowB[0], b1 = rowB[1], b2 = rowB[2];
            #pragma unroll
            for (int s = 0; s < 4; ++s) {
                float aA = a2.x
                    + a0.x * zr[s][0] + a0.y * zr[s][1] + a0.z * zr[s][2] + a0.w * zr[s][3]
                    + a1.x * zr[s][4] + a1.y * zr[s][5] + a1.z * zr[s][6] + a1.w * zr[s][7];
                float aB = b2.x
                    + b0.x * zr[s][0] + b0.y * zr[s][1] + b0.z * zr[s][2] + b0.w * zr[s][3]
                    + b1.x * zr[s][4] + b1.y * zr[s][5] + b1.z * zr[s][6] + b1.w * zr[s][7];
                y1p[s][icp][1 + oy][1 + ox] = pk2(fmaxf(aA, 0.f), fmaxf(aB, 0.f));
            }
        }
    }
    __syncthreads();

    // phase 1: convT2 fused 4-class 2x2 tiles via v_dot2_f32_bf16.
    {
        int pos = (L < 49) ? L : 48;
        int s = wv, m = pos / 7, n = pos % 7;
        float acc[4][8];
        #pragma unroll
        for (int oc = 0; oc < 8; ++oc) {
            float b = db2[oc];
            acc[0][oc] = b; acc[1][oc] = b; acc[2][oc] = b; acc[3][oc] = b;
        }
        #pragma unroll 2
        for (int icp = 0; icp < 8; ++icp) {
            unsigned int yv[3][3];
            #pragma unroll
            for (int ry = 0; ry < 3; ++ry)
                #pragma unroll
                for (int rx = 0; rx < 3; ++rx)
                    yv[ry][rx] = y1p[s][icp][m + ry][n + rx];
            #pragma unroll
            for (int oc = 0; oc < 8; ++oc) {
                const unsigned int* p00 = Wp2 + (icp * 8 + oc) * 9;
                const unsigned int* p01 = Wp2 + 576 + (icp * 8 + oc) * 6;
                const unsigned int* p10 = Wp2 + 960 + (icp * 8 + oc) * 6;
                const unsigned int* p11 = Wp2 + 1344 + (icp * 8 + oc) * 4;
                #pragma unroll
                for (int dy = 0; dy < 3; ++dy)
                    #pragma unroll
                    for (int dx = 0; dx < 3; ++dx)
                        acc[0][oc] = dot2bfs(p00[dy * 3 + dx], yv[dy][dx], acc[0][oc]);
                #pragma unroll
                for (int dy = 0; dy < 3; ++dy)
                    #pragma unroll
                    for (int dx = 0; dx < 2; ++dx)
                        acc[1][oc] = dot2bfs(p01[dy * 2 + dx], yv[dy][dx + 1], acc[1][oc]);
                #pragma unroll
                for (int dy = 0; dy < 2; ++dy)
                    #pragma unroll
                    for (int dx = 0; dx < 3; ++dx)
                        acc[2][oc] = dot2bfs(p10[dy * 3 + dx], yv[dy + 1][dx], acc[2][oc]);
                #pragma unroll
                for (int dy = 0; dy < 2; ++dy)
                    #pragma unroll
                    for (int dx = 0; dx < 2; ++dx)
                        acc[3][oc] = dot2bfs(p11[dy * 2 + dx], yv[dy + 1][dx + 1], acc[3][oc]);
            }
        }
        if (L < 49) {
            #pragma unroll
            for (int p = 0; p < 4; ++p) {
                y2p[s][p][1 + 2 * m][1 + 2 * n] = pk2(fmaxf(acc[0][2 * p], 0.f), fmaxf(acc[0][2 * p + 1], 0.f));
                y2p[s][p][1 + 2 * m][2 + 2 * n] = pk2(fmaxf(acc[1][2 * p], 0.f), fmaxf(acc[1][2 * p + 1], 0.f));
                y2p[s][p][2 + 2 * m][1 + 2 * n] = pk2(fmaxf(acc[2][2 * p], 0.f), fmaxf(acc[2][2 * p + 1], 0.f));
                y2p[s][p][2 + 2 * m][2 + 2 * n] = pk2(fmaxf(acc[3][2 * p], 0.f), fmaxf(acc[3][2 * p + 1], 0.f));
            }
        }
    }
    __syncthreads();

    // phase 2: convT3 fused 4-class 2x2 tiles + sigmoid + lhood (fp32 weights)
    float part = 0.f;
    {
        float b3v = db3[0];
        const float* q00 = Wc3;
        const float* q01 = Wc3 + 72;
        const float* q10 = Wc3 + 120;
        const float* q11 = Wc3 + 168;
        #pragma unroll 1
        for (int ch = 0; ch < 4; ++ch) {
            int g = ch * 256 + tid;
            if (g < 784) {
                int s2 = g / 196, r2 = g % 196, m = r2 / 14, n = r2 % 14;
                float o00 = b3v, o01 = b3v, o10 = b3v, o11 = b3v;
                #pragma unroll
                for (int icp = 0; icp < 4; ++icp) {
                    float ylo[3][3], yhi[3][3];
                    #pragma unroll
                    for (int ry = 0; ry < 3; ++ry)
                        #pragma unroll
                        for (int rx = 0; rx < 3; ++rx) {
                            unsigned int u = y2p[s2][icp][m + ry][n + rx];
                            ylo[ry][rx] = __uint_as_float(u << 16);
                            yhi[ry][rx] = __uint_as_float(u & 0xffff0000u);
                        }
                    int ic0 = 2 * icp, ic1 = 2 * icp + 1;
                    #pragma unroll
                    for (int dy = 0; dy < 3; ++dy)
                        #pragma unroll
                        for (int dx = 0; dx < 3; ++dx) {
                            o00 = fmaf(q00[ic0 * 9 + dy * 3 + dx], ylo[dy][dx], o00);
                            o00 = fmaf(q00[ic1 * 9 + dy * 3 + dx], yhi[dy][dx], o00);
                        }
                    #pragma unroll
                    for (int dy = 0; dy < 3; ++dy)
                        #pragma unroll
                        for (int dx = 0; dx < 2; ++dx) {
                            o01 = fmaf(q01[ic0 * 6 + dy * 2 + dx], ylo[dy][dx + 1], o01);
                            o01 = fmaf(q01[ic1 * 6 + dy * 2 + dx], yhi[dy][dx + 1], o01);
                        }
                    #pragma unroll
                    for (int dy = 0; dy < 2; ++dy)
                        #pragma unroll
                        for (int dx = 0; dx < 3; ++dx) {
                            o10 = fmaf(q10[ic0 * 6 + dy * 3 + dx], ylo[dy + 1][dx], o10);
                            o10 = fmaf(q10[ic1 * 6 + dy * 3 + dx], yhi[dy + 1][dx], o10);
                        }
                    #pragma unroll
                    for (int dy = 0; dy < 2; ++dy)
                        #pragma unroll
                        for (int dx = 0; dx < 2; ++dx) {
                            o11 = fmaf(q11[ic0 * 4 + dy * 2 + dx], ylo[dy + 1][dx + 1], o11);
                            o11 = fmaf(q11[ic1 * 4 + dy * 2 + dx], yhi[dy + 1][dx + 1], o11);
                        }
                }
                float p00s = 1.f / (1.f + __expf(-o00));
                float p01s = 1.f / (1.f + __expf(-o01));
                float p10s = 1.f / (1.f + __expf(-o10));
                float p11s = 1.f / (1.f + __expf(-o11));
                size_t base = (size_t)blk * 3136 + s2 * 784 + 2 * m * 28 + 2 * n;
                *(float2*)(xrec + base)      = float2{p00s, p01s};
                *(float2*)(xrec + base + 28) = float2{p10s, p11s};
                float2 x0 = *(const float2*)(X + base);
                float2 x1 = *(const float2*)(X + base + 28);
                part += __logf(EPSL + p00s) * x0.x + __logf(EPSL + 1.f - p00s) * (1.f - x0.x);
                part += __logf(EPSL + p01s) * x0.y + __logf(EPSL + 1.f - p01s) * (1.f - x0.y);
                part += __logf(EPSL + p10s) * x1.x + __logf(EPSL + 1.f - p10s) * (1.f - x1.x);
                part += __logf(EPSL + p11s) * x1.y + __logf(EPSL + 1.f - p11s) * (1.f - x1.y);
            }
        }
    }
    // per-wave shuffle reduce, then one cross-wave combine
    part += __shfl_down(part, 32);
    part += __shfl_down(part, 16);
    part += __shfl_down(part, 8);
    part += __shfl_down(part, 4);
    part += __shfl_down(part, 2);
    part += __shfl_down(part, 1);
    if (L == 0) red4[wv] = part;
    __syncthreads();
    if (tid == 0) lhp[blk] = (red4[0] + red4[1]) + (red4[2] + red4[3]);
}

// =====================================================================
// Finalize
// =====================================================================
__global__ __launch_bounds__(256) void fin_kernel(
    const float* __restrict__ lhp, const float* __restrict__ klp,
    float* __restrict__ out)
{
    __shared__ double red[256];
    int tid = threadIdx.x;
    double s = 0.0;
    for (int i = tid; i < 3200; i += 256) s += (double)lhp[i];
    red[tid] = s;
    __syncthreads();
    for (int st = 128; st > 0; st >>= 1) {
        if (tid < st) red[tid] += red[tid + st];
        __syncthreads();
    }
    double lh = red[0];
    __syncthreads();
    red[tid] = (double)klp[tid];
    __syncthreads();
    for (int st = 128; st > 0; st >>= 1) {
        if (tid < st) red[tid] += red[tid + st];
        __syncthreads();
    }
    if (tid == 0) {
        out[LH_OFF] = (float)(lh / 256.0);
        out[KL_OFF] = (float)(red[0] / 2048.0);
    }
}

extern "C" void kernel_launch(void* const* d_in, const int* in_sizes, int n_in,
                              void* d_out, int out_size, void* d_ws, size_t ws_size,
                              hipStream_t stream) {
    const float* X     = (const float*)d_in[0];
    const float* eps   = (const float*)d_in[1];
    const float* ew1   = (const float*)d_in[2];
    const float* eb1   = (const float*)d_in[3];
    const float* ew2   = (const float*)d_in[4];
    const float* eb2   = (const float*)d_in[5];
    const float* ew3   = (const float*)d_in[6];
    const float* eb3   = (const float*)d_in[7];
    const float* fc1w  = (const float*)d_in[8];
    const float* fc1b  = (const float*)d_in[9];
    const float* fc2w  = (const float*)d_in[10];
    const float* fc2b  = (const float*)d_in[11];
    const float* fw1   = (const float*)d_in[12];
    const float* fb1   = (const float*)d_in[13];
    const float* fw2   = (const float*)d_in[14];
    const float* fb2   = (const float*)d_in[15];
    const float* fw3   = (const float*)d_in[16];
    const float* fb3   = (const float*)d_in[17];
    const float* fc3w  = (const float*)d_in[18];
    const float* fc3b  = (const float*)d_in[19];
    const float* dw1   = (const float*)d_in[20];
    const float* db1   = (const float*)d_in[21];
    const float* dw2   = (const float*)d_in[22];
    const float* db2   = (const float*)d_in[23];
    const float* dw3   = (const float*)d_in[24];
    const float* db3   = (const float*)d_in[25];

    float* out = (float*)d_out;
    char* ws = (char*)d_ws;
    float* lhp = (float*)ws;
    float* klp = (float*)(ws + 12800);
    float* z0  = (float*)(ws + 13824);
    float* M1p = (float*)(ws + 22016);
    unsigned int* Wp2 = (unsigned int*)(ws + 59648);
    float* Wc3 = (float*)(ws + 72448);

    prep_kernel<<<51, 256, 0, stream>>>(fc3w, fc3b, dw1, db1, dw2, dw3, M1p, Wp2, Wc3);
    enc_kernel<<<256, 256, 0, stream>>>(X, eps, ew1, eb1, ew2, eb2, ew3, eb3,
                                        fc1w, fc1b, fc2w, fc2b, out, z0, klp);
    ode_kernel<<<256, 256, 0, stream>>>(z0, fw1, fb1, fw2, fb2, fw3, fb3, out + ZT_OFF);
    dec_kernel<<<3200, 256, 0, stream>>>(M1p, out + ZT_OFF, Wp2, db2, Wc3, db3,
                                         X, out + XREC_OFF, lhp);
    fin_kernel<<<1, 256, 0, stream>>>(lhp, klp, out);
}

// Round 6
// 417.316 us; speedup vs baseline: 1.4466x; 1.1380x over previous
//
#include <hip/hip_runtime.h>
#include <math.h>

#define DT 0.1f
#define EPSL 1e-5f

// ---- output layout (float32, concatenated in reference return order) ----
#define XREC_OFF 0
#define QM_OFF   10035200
#define QV_OFF   10037248
#define ZT_OFF   10039296
#define LH_OFF   10141696
#define KL_OFF   10141697

// ---- workspace layout (bytes) ----
// lhp  float[3200]   @ 0
// klp  float[256]    @ 12800
// z0   float[2048]   @ 13824
// M1p  float[784*12] @ 22016
// Wp2  u32[1600]     @ 59648   (bf16-paired convT2 weights)
// Wc3  float[200]    @ 72448

__device__ __forceinline__ unsigned short f2bf(float x) {
    unsigned int u = __float_as_uint(x);
    u += 0x7fffu + ((u >> 16) & 1u);
    return (unsigned short)(u >> 16);
}
__device__ __forceinline__ float bf2f(unsigned short h) {
    return __uint_as_float(((unsigned int)h) << 16);
}
__device__ __forceinline__ unsigned int pk2(float lo, float hi) {
    return (unsigned int)f2bf(lo) | ((unsigned int)f2bf(hi) << 16);
}
// D = S0.bf16[0]*S1.bf16[0] + S0.bf16[1]*S1.bf16[1] + S2  (exact products, f32 acc)
__device__ __forceinline__ float dot2bfs(unsigned int w, unsigned int y, float c) {
    float d;
    asm("v_dot2_f32_bf16 %0, %1, %2, %3" : "=v"(d) : "s"(w), "v"(y), "v"(c));
    return d;
}

// =====================================================================
// Prep: build M1p + parity-class repacked decoder weights.
// =====================================================================
__global__ __launch_bounds__(256) void prep_kernel(
    const float* __restrict__ fc3w, const float* __restrict__ fc3b,
    const float* __restrict__ dw1, const float* __restrict__ db1,
    const float* __restrict__ dw2, const float* __restrict__ dw3,
    float* __restrict__ M1p, unsigned int* __restrict__ Wp2, float* __restrict__ Wc3)
{
    int idx = blockIdx.x * 256 + threadIdx.x;
    if (idx < 9408) {                       // M1p [784][12]
        int m = idx / 12, j = idx % 12;
        float acc = 0.f;
        if (j < 9) {
            int oc = m / 49, r = m % 49, oy = r / 7, ox = r % 7;
            acc = (j == 8) ? db1[oc] : 0.f;
            for (int ky = 0; ky < 5; ++ky) {
                int ty = oy + ky - 2;
                if (ty < 0 || (ty & 1)) continue;
                int iy = ty >> 1; if (iy >= 4) continue;
                for (int kx = 0; kx < 5; ++kx) {
                    int tx = ox + kx - 2;
                    if (tx < 0 || (tx & 1)) continue;
                    int ix = tx >> 1; if (ix >= 4) continue;
                    for (int ic = 0; ic < 32; ++ic) {
                        float wv = dw1[((oc * 32 + ic) * 5 + ky) * 5 + kx];
                        int mi = ic * 16 + iy * 4 + ix;
                        acc += wv * ((j < 8) ? fc3w[mi * 8 + j] : fc3b[mi]);
                    }
                }
            }
        }
        M1p[idx] = acc;
    } else if (idx < 9408 + 3200) {         // Wp2 repack, dw2 [oc=8][ic=16][ky][kx]
        int iw = idx - 9408;
        int kx = iw % 5, t1 = iw / 5, ky = t1 % 5, t2 = t1 / 5, ic = t2 % 16, oc = t2 / 16;
        int cy = ky & 1, cx = kx & 1, dy = ky >> 1, dx = kx >> 1;
        int ny = cy ? 2 : 3, nx = cx ? 2 : 3, nt = ny * nx;
        const int off2[4] = {0, 576, 960, 1344};   // u32-pair units
        int icp = ic >> 1, half = ic & 1;
        unsigned short* Wp2h = (unsigned short*)Wp2;
        Wp2h[(off2[cy * 2 + cx] + (icp * 8 + oc) * nt + dy * nx + dx) * 2 + half] = f2bf(dw2[iw]);
    } else if (idx < 9408 + 3200 + 200) {   // Wc3 repack (fp32: precision hedge)
        int iw = idx - 12608;
        int kx = iw % 5, t1 = iw / 5, ky = t1 % 5, ic = t1 / 5;
        int cy = ky & 1, cx = kx & 1, dy = ky >> 1, dx = kx >> 1;
        int ny = cy ? 2 : 3, nx = cx ? 2 : 3, nt = ny * nx;
        const int off3[4] = {0, 72, 120, 168};
        Wc3[off3[cy * 2 + cx] + ic * nt + dy * nx + dx] = dw3[iw];
    }
}

// =====================================================================
// Encoder v3: oc-major thread mapping — each thread's outputs share one
// oc, so per-ic weights load ONCE into registers (w ds-reads -60%).
// Per-output accumulation order identical to v2 -> bit-exact fp32.
// =====================================================================
__global__ __launch_bounds__(256) void enc_kernel(
    const float* __restrict__ X, const float* __restrict__ eps,
    const float* __restrict__ w1, const float* __restrict__ b1,
    const float* __restrict__ w2, const float* __restrict__ b2,
    const float* __restrict__ w3, const float* __restrict__ b3,
    const float* __restrict__ fc1w, const float* __restrict__ fc1b,
    const float* __restrict__ fc2w, const float* __restrict__ fc2b,
    float* __restrict__ out, float* __restrict__ z0, float* __restrict__ klp)
{
    __shared__ float imgp[33][33];
    __shared__ float a1p[8][17][17];
    __shared__ float a2p[16][11][11];
    __shared__ float h[512];
    __shared__ float w1s[200];
    __shared__ float w2s[3200];
    __shared__ float w3s[12800];
    __shared__ float fcred[16];
    __shared__ float kl_s[8];
    int n = blockIdx.x, tid = threadIdx.x;

    for (int i = tid; i < 1089; i += 256) ((float*)imgp)[i] = 0.f;
    for (int i = tid; i < 2312; i += 256) ((float*)a1p)[i] = 0.f;
    for (int i = tid; i < 1936; i += 256) ((float*)a2p)[i] = 0.f;
    for (int i = tid; i < 50;   i += 256) ((float4*)w1s)[i] = ((const float4*)w1)[i];
    for (int i = tid; i < 800;  i += 256) ((float4*)w2s)[i] = ((const float4*)w2)[i];
    for (int i = tid; i < 3200; i += 256) ((float4*)w3s)[i] = ((const float4*)w3)[i];
    __syncthreads();

    const float* xi = X + (size_t)n * 39200;
    for (int i = tid; i < 784; i += 256) imgp[2 + i / 28][2 + i % 28] = xi[i];
    __syncthreads();

    // conv1: 8 oc x 196 px; thread -> (oc = tid>>5, px = (tid&31)+32k)
    {
        int oc = tid >> 5, p0 = tid & 31;
        float wr[25];
        #pragma unroll
        for (int q = 0; q < 25; ++q) wr[q] = w1s[oc * 25 + q];
        float bb = b1[oc];
        #pragma unroll 1
        for (int k = 0; k < 7; ++k) {
            int px = p0 + 32 * k;
            if (px < 196) {
                int oy = px / 14, ox = px % 14;
                float acc = bb;
                #pragma unroll
                for (int ky = 0; ky < 5; ++ky)
                    #pragma unroll
                    for (int kx = 0; kx < 5; ++kx)
                        acc = fmaf(wr[ky * 5 + kx], imgp[2 * oy + ky][2 * ox + kx], acc);
                a1p[oc][2 + oy][2 + ox] = fmaxf(acc, 0.f);
            }
        }
    }
    __syncthreads();

    // conv2: 16 oc x 49 px; thread -> (oc = tid>>4, px = (tid&15)+16k)
    {
        int oc = tid >> 4, p0 = tid & 15;
        float bb = b2[oc];
        float acc[4] = {bb, bb, bb, bb};
        #pragma unroll 1
        for (int ic = 0; ic < 8; ++ic) {
            float wr[25];
            #pragma unroll
            for (int q = 0; q < 25; ++q) wr[q] = w2s[(oc * 8 + ic) * 25 + q];
            #pragma unroll
            for (int k = 0; k < 4; ++k) {
                int px = p0 + 16 * k;
                if (px < 49) {
                    int oy = px / 7, ox = px % 7;
                    #pragma unroll
                    for (int ky = 0; ky < 5; ++ky)
                        #pragma unroll
                        for (int kx = 0; kx < 5; ++kx)
                            acc[k] = fmaf(wr[ky * 5 + kx], a1p[ic][2 * oy + ky][2 * ox + kx], acc[k]);
                }
            }
        }
        #pragma unroll
        for (int k = 0; k < 4; ++k) {
            int px = p0 + 16 * k;
            if (px < 49) {
                int oy = px / 7, ox = px % 7;
                a2p[oc][2 + oy][2 + ox] = fmaxf(acc[k], 0.f);
            }
        }
    }
    __syncthreads();

    // conv3: 32 oc x 16 px; thread -> (oc = tid>>3, px = (tid&7)+8k)
    {
        int oc = tid >> 3, p0 = tid & 7;
        float bb = b3[oc];
        float acc[2] = {bb, bb};
        #pragma unroll 1
        for (int ic = 0; ic < 16; ++ic) {
            float wr[25];
            #pragma unroll
            for (int q = 0; q < 25; ++q) wr[q] = w3s[(oc * 16 + ic) * 25 + q];
            #pragma unroll
            for (int k = 0; k < 2; ++k) {
                int px = p0 + 8 * k;
                int oy = px >> 2, ox = px & 3;
                #pragma unroll
                for (int ky = 0; ky < 5; ++ky)
                    #pragma unroll
                    for (int kx = 0; kx < 5; ++kx)
                        acc[k] = fmaf(wr[ky * 5 + kx], a2p[ic][2 * oy + ky][2 * ox + kx], acc[k]);
            }
        }
        #pragma unroll
        for (int k = 0; k < 2; ++k) {
            int px = p0 + 8 * k;
            h[oc * 16 + px] = fmaxf(acc[k], 0.f);
        }
    }
    __syncthreads();

    if (tid < 128) {
        int wv = tid >> 6, L = tid & 63, o = L >> 3, rr = L & 7;
        const float* fw = (wv ? fc2w : fc1w) + o * 512;
        float p = 0.f;
        #pragma unroll 8
        for (int j = 0; j < 64; ++j) {
            int k = rr + 8 * j;
            p = fmaf(fw[k], h[k], p);
        }
        p += __shfl_down(p, 4, 8);
        p += __shfl_down(p, 2, 8);
        p += __shfl_down(p, 1, 8);
        if (rr == 0) fcred[wv * 8 + o] = p;
    }
    __syncthreads();
    if (tid < 8) {
        float m = fc1b[tid] + fcred[tid];
        float lv = fc2b[tid] + fcred[8 + tid];
        float v = fmaxf(lv, 0.f) + log1pf(expf(-fabsf(lv)));
        float z = m + eps[n * 8 + tid] * v;
        out[QM_OFF + n * 8 + tid] = m;
        out[QV_OFF + n * 8 + tid] = v;
        z0[n * 8 + tid] = z;
        kl_s[tid] = -logf(v) + 0.5f * (v * v + m * m) - 0.5f;
    }
    __syncthreads();
    if (tid == 0) {
        float s = 0.f;
        for (int i = 0; i < 8; ++i) s += kl_s[i];
        klp[n] = s;
    }
}

// =====================================================================
// ODE v4 (restored — known 120 us): 4 waves per sample, k-split 25/wave.
// =====================================================================
__device__ __forceinline__ float rl(float v, int lane) {
    return __uint_as_float(__builtin_amdgcn_readlane(__float_as_uint(v), lane));
}

__global__ __launch_bounds__(256, 1) void ode_kernel(
    const float* __restrict__ z0,
    const float* __restrict__ fw1, const float* __restrict__ fb1,
    const float* __restrict__ fw2, const float* __restrict__ fb2,
    const float* __restrict__ fw3, const float* __restrict__ fb3,
    float* __restrict__ ztg)
{
    __shared__ float part2[4][104];
    __shared__ float part3[4][8];
    int n = blockIdx.x, tid = threadIdx.x;
    int w = tid >> 6, L = tid & 63;
    int i3 = L & 7;
    bool act25 = (L < 25);
    int j1 = 25 * w + L;
    bool hiv = (L < 36);
    int jA = L, jB = L + 64;
    int k0 = 25 * w;

    float w1r[8];
    float b1A = 0.f, b2A = 0.f;
    if (act25) {
        b1A = fb1[j1];
        b2A = fb2[j1];
        #pragma unroll
        for (int k = 0; k < 8; ++k) w1r[k] = fw1[j1 * 8 + k];
    } else {
        #pragma unroll
        for (int k = 0; k < 8; ++k) w1r[k] = 0.f;
    }
    float w2x[25], w2y[25], w3r[25];
    #pragma unroll
    for (int kk = 0; kk < 25; ++kk) {
        w2x[kk] = fw2[jA * 100 + k0 + kk];
        w2y[kk] = hiv ? fw2[jB * 100 + k0 + kk] : 0.f;
        w3r[kk] = fw3[i3 * 100 + k0 + kk];
    }
    float b3r = fb3[i3];

    float zc = z0[n * 8 + i3];
    if (tid < 8) ztg[n * 400 + tid] = zc;
    float vu[8];
    #pragma unroll
    for (int i = 0; i < 8; ++i) vu[i] = rl(zc, i);

    #pragma unroll 1
    for (int t = 1; t < 50; ++t) {
        float zsum = 0.f;
        #pragma unroll 1
        for (int st = 0; st < 4; ++st) {
            float aA = 0.f;
            if (act25) {
                float a = b1A;
                #pragma unroll
                for (int k = 0; k < 8; ++k) a = fmaf(w1r[k], vu[k], a);
                aA = fmaxf(a, 0.f);
            }

            float ha[4] = {0.f, 0.f, 0.f, 0.f};
            float hb[4] = {0.f, 0.f, 0.f, 0.f};
            #pragma unroll
            for (int kk = 0; kk < 25; ++kk) {
                float s = rl(aA, kk);
                ha[kk & 3] = fmaf(w2x[kk], s, ha[kk & 3]);
                hb[kk & 3] = fmaf(w2y[kk], s, hb[kk & 3]);
            }
            part2[w][L] = (ha[0] + ha[1]) + (ha[2] + ha[3]);
            if (hiv) part2[w][64 + L] = (hb[0] + hb[1]) + (hb[2] + hb[3]);
            __syncthreads();

            float h2v = 0.f;
            if (act25) {
                float sA = (part2[0][j1] + part2[1][j1]) + (part2[2][j1] + part2[3][j1]);
                h2v = fmaxf(b2A + sA, 0.f);
            }

            float oa[4] = {0.f, 0.f, 0.f, 0.f};
            #pragma unroll
            for (int kk = 0; kk < 25; ++kk) {
                float s = rl(h2v, kk);
                oa[kk & 3] = fmaf(w3r[kk], s, oa[kk & 3]);
            }
            if (L < 8) part3[w][L] = (oa[0] + oa[1]) + (oa[2] + oa[3]);
            __syncthreads();

            float o = b3r + ((part3[0][i3] + part3[1][i3]) + (part3[2][i3] + part3[3][i3]));
            float cw = (st == 0 || st == 3) ? (DT / 6.f) : (DT / 3.f);
            zsum = fmaf(cw, o, zsum);
            float vn;
            if (st < 3) {
                float cin = (st == 2) ? DT : 0.5f * DT;
                vn = fmaf(cin, o, zc);
            } else {
                zc = zc + zsum;
                vn = zc;
                if (tid < 8) ztg[n * 400 + t * 8 + tid] = zc;
            }
            #pragma unroll
            for (int i = 0; i < 8; ++i) vu[i] = rl(vn, i);
        }
    }
}

// =====================================================================
// Decoder v9 (restored R2-exact): dot2 phase 1, y1p stride 10.
// =====================================================================
__global__ __launch_bounds__(256, 5) void dec_kernel(
    const float* __restrict__ M1p, const float* __restrict__ zt,
    const unsigned int* __restrict__ Wp2, const float* __restrict__ db2,
    const float* __restrict__ Wc3, const float* __restrict__ db3,
    const float* __restrict__ X, float* __restrict__ xrec,
    float* __restrict__ lhp)
{
    __shared__ __align__(16) unsigned int y1p[4][8][9][10];    // bf16 ic-pairs, 11520 B
    __shared__ __align__(16) unsigned int y2p[4][4][16][17];   // bf16 ic-pairs, 17408 B
    __shared__ float red4[4];
    int blk = blockIdx.x, tid = threadIdx.x;
    int wv = tid >> 6, L = tid & 63;

    {
        uint4 z4 = uint4{0u, 0u, 0u, 0u};
        for (int i = tid; i < 720;  i += 256) ((uint4*)y1p)[i] = z4;
        for (int i = tid; i < 1088; i += 256) ((uint4*)y2p)[i] = z4;
    }
    __syncthreads();

    // phase 0: y1 = relu(M1 @ z + b), two channels (one pair) per work item
    {
        float zr[4][8];
        const float* zp = zt + (size_t)blk * 32;
        #pragma unroll
        for (int s = 0; s < 4; ++s)
            #pragma unroll
            for (int jj = 0; jj < 8; ++jj) zr[s][jj] = zp[s * 8 + jj];
        for (int m2 = tid; m2 < 392; m2 += 256) {
            int icp = m2 / 49, r = m2 % 49, oy = r / 7, ox = r % 7;
            const float4* rowA = (const float4*)(M1p + (size_t)((icp * 2) * 49 + r) * 12);
            const float4* rowB = (const float4*)(M1p + (size_t)((icp * 2 + 1) * 49 + r) * 12);
            float4 a0 = rowA[0], a1 = rowA[1], a2 = rowA[2];
            float4 b0 = rowB[0], b1 = rowB[1], b2 = rowB[2];
            #pragma unroll
            for (int s = 0; s < 4; ++s) {
                float aA = a2.x
                    + a0.x * zr[s][0] + a0.y * zr[s][1] + a0.z * zr[s][2] + a0.w * zr[s][3]
                    + a1.x * zr[s][4] + a1.y * zr[s][5] + a1.z * zr[s][6] + a1.w * zr[s][7];
                float aB = b2.x
                    + b0.x * zr[s][0] + b0.y * zr[s][1] + b0.z * zr[s][2] + b0.w * zr[s][3]
                    + b1.x * zr[s][4] + b1.y * zr[s][5] + b1.z * zr[s][6] + b1.w * zr[s][7];
                y1p[s][icp][1 + oy][1 + ox] = pk2(fmaxf(aA, 0.f), fmaxf(aB, 0.f));
            }
        }
    }
    __syncthreads();

    // phase 1: convT2 fused 4-class 2x2 tiles via v_dot2_f32_bf16.
    {
        int pos = (L < 49) ? L : 48;
        int s = wv, m = pos / 7, n = pos % 7;
        float acc[4][8];
        #pragma unroll
        for (int oc = 0; oc < 8; ++oc) {
            float b = db2[oc];
            acc[0][oc] = b; acc[1][oc] = b; acc[2][oc] = b; acc[3][oc] = b;
        }
        #pragma unroll 2
        for (int icp = 0; icp < 8; ++icp) {
            unsigned int yv[3][3];
            #pragma unroll
            for (int ry = 0; ry < 3; ++ry)
                #pragma unroll
                for (int rx = 0; rx < 3; ++rx)
                    yv[ry][rx] = y1p[s][icp][m + ry][n + rx];
            #pragma unroll
            for (int oc = 0; oc < 8; ++oc) {
                const unsigned int* p00 = Wp2 + (icp * 8 + oc) * 9;
                const unsigned int* p01 = Wp2 + 576 + (icp * 8 + oc) * 6;
                const unsigned int* p10 = Wp2 + 960 + (icp * 8 + oc) * 6;
                const unsigned int* p11 = Wp2 + 1344 + (icp * 8 + oc) * 4;
                #pragma unroll
                for (int dy = 0; dy < 3; ++dy)
                    #pragma unroll
                    for (int dx = 0; dx < 3; ++dx)
                        acc[0][oc] = dot2bfs(p00[dy * 3 + dx], yv[dy][dx], acc[0][oc]);
                #pragma unroll
                for (int dy = 0; dy < 3; ++dy)
                    #pragma unroll
                    for (int dx = 0; dx < 2; ++dx)
                        acc[1][oc] = dot2bfs(p01[dy * 2 + dx], yv[dy][dx + 1], acc[1][oc]);
                #pragma unroll
                for (int dy = 0; dy < 2; ++dy)
                    #pragma unroll
                    for (int dx = 0; dx < 3; ++dx)
                        acc[2][oc] = dot2bfs(p10[dy * 3 + dx], yv[dy + 1][dx], acc[2][oc]);
                #pragma unroll
                for (int dy = 0; dy < 2; ++dy)
                    #pragma unroll
                    for (int dx = 0; dx < 2; ++dx)
                        acc[3][oc] = dot2bfs(p11[dy * 2 + dx], yv[dy + 1][dx + 1], acc[3][oc]);
            }
        }
        if (L < 49) {
            #pragma unroll
            for (int p = 0; p < 4; ++p) {
                y2p[s][p][1 + 2 * m][1 + 2 * n] = pk2(fmaxf(acc[0][2 * p], 0.f), fmaxf(acc[0][2 * p + 1], 0.f));
                y2p[s][p][1 + 2 * m][2 + 2 * n] = pk2(fmaxf(acc[1][2 * p], 0.f), fmaxf(acc[1][2 * p + 1], 0.f));
                y2p[s][p][2 + 2 * m][1 + 2 * n] = pk2(fmaxf(acc[2][2 * p], 0.f), fmaxf(acc[2][2 * p + 1], 0.f));
                y2p[s][p][2 + 2 * m][2 + 2 * n] = pk2(fmaxf(acc[3][2 * p], 0.f), fmaxf(acc[3][2 * p + 1], 0.f));
            }
        }
    }
    __syncthreads();

    // phase 2: convT3 fused 4-class 2x2 tiles + sigmoid + lhood (fp32 weights)
    float part = 0.f;
    {
        float b3v = db3[0];
        const float* q00 = Wc3;
        const float* q01 = Wc3 + 72;
        const float* q10 = Wc3 + 120;
        const float* q11 = Wc3 + 168;
        #pragma unroll 1
        for (int ch = 0; ch < 4; ++ch) {
            int g = ch * 256 + tid;
            if (g < 784) {
                int s2 = g / 196, r2 = g % 196, m = r2 / 14, n = r2 % 14;
                float o00 = b3v, o01 = b3v, o10 = b3v, o11 = b3v;
                #pragma unroll
                for (int icp = 0; icp < 4; ++icp) {
                    float ylo[3][3], yhi[3][3];
                    #pragma unroll
                    for (int ry = 0; ry < 3; ++ry)
                        #pragma unroll
                        for (int rx = 0; rx < 3; ++rx) {
                            unsigned int u = y2p[s2][icp][m + ry][n + rx];
                            ylo[ry][rx] = __uint_as_float(u << 16);
                            yhi[ry][rx] = __uint_as_float(u & 0xffff0000u);
                        }
                    int ic0 = 2 * icp, ic1 = 2 * icp + 1;
                    #pragma unroll
                    for (int dy = 0; dy < 3; ++dy)
                        #pragma unroll
                        for (int dx = 0; dx < 3; ++dx) {
                            o00 = fmaf(q00[ic0 * 9 + dy * 3 + dx], ylo[dy][dx], o00);
                            o00 = fmaf(q00[ic1 * 9 + dy * 3 + dx], yhi[dy][dx], o00);
                        }
                    #pragma unroll
                    for (int dy = 0; dy < 3; ++dy)
                        #pragma unroll
                        for (int dx = 0; dx < 2; ++dx) {
                            o01 = fmaf(q01[ic0 * 6 + dy * 2 + dx], ylo[dy][dx + 1], o01);
                            o01 = fmaf(q01[ic1 * 6 + dy * 2 + dx], yhi[dy][dx + 1], o01);
                        }
                    #pragma unroll
                    for (int dy = 0; dy < 2; ++dy)
                        #pragma unroll
                        for (int dx = 0; dx < 3; ++dx) {
                            o10 = fmaf(q10[ic0 * 6 + dy * 3 + dx], ylo[dy + 1][dx], o10);
                            o10 = fmaf(q10[ic1 * 6 + dy * 3 + dx], yhi[dy + 1][dx], o10);
                        }
                    #pragma unroll
                    for (int dy = 0; dy < 2; ++dy)
                        #pragma unroll
                        for (int dx = 0; dx < 2; ++dx) {
                            o11 = fmaf(q11[ic0 * 4 + dy * 2 + dx], ylo[dy + 1][dx + 1], o11);
                            o11 = fmaf(q11[ic1 * 4 + dy * 2 + dx], yhi[dy + 1][dx + 1], o11);
                        }
                }
                float p00s = 1.f / (1.f + __expf(-o00));
                float p01s = 1.f / (1.f + __expf(-o01));
                float p10s = 1.f / (1.f + __expf(-o10));
                float p11s = 1.f / (1.f + __expf(-o11));
                size_t base = (size_t)blk * 3136 + s2 * 784 + 2 * m * 28 + 2 * n;
                *(float2*)(xrec + base)      = float2{p00s, p01s};
                *(float2*)(xrec + base + 28) = float2{p10s, p11s};
                float2 x0 = *(const float2*)(X + base);
                float2 x1 = *(const float2*)(X + base + 28);
                part += __logf(EPSL + p00s) * x0.x + __logf(EPSL + 1.f - p00s) * (1.f - x0.x);
                part += __logf(EPSL + p01s) * x0.y + __logf(EPSL + 1.f - p01s) * (1.f - x0.y);
                part += __logf(EPSL + p10s) * x1.x + __logf(EPSL + 1.f - p10s) * (1.f - x1.x);
                part += __logf(EPSL + p11s) * x1.y + __logf(EPSL + 1.f - p11s) * (1.f - x1.y);
            }
        }
    }
    // per-wave shuffle reduce, then one cross-wave combine
    part += __shfl_down(part, 32);
    part += __shfl_down(part, 16);
    part += __shfl_down(part, 8);
    part += __shfl_down(part, 4);
    part += __shfl_down(part, 2);
    part += __shfl_down(part, 1);
    if (L == 0) red4[wv] = part;
    __syncthreads();
    if (tid == 0) lhp[blk] = (red4[0] + red4[1]) + (red4[2] + red4[3]);
}

// =====================================================================
// Finalize
// =====================================================================
__global__ __launch_bounds__(256) void fin_kernel(
    const float* __restrict__ lhp, const float* __restrict__ klp,
    float* __restrict__ out)
{
    __shared__ double red[256];
    int tid = threadIdx.x;
    double s = 0.0;
    for (int i = tid; i < 3200; i += 256) s += (double)lhp[i];
    red[tid] = s;
    __syncthreads();
    for (int st = 128; st > 0; st >>= 1) {
        if (tid < st) red[tid] += red[tid + st];
        __syncthreads();
    }
    double lh = red[0];
    __syncthreads();
    red[tid] = (double)klp[tid];
    __syncthreads();
    for (int st = 128; st > 0; st >>= 1) {
        if (tid < st) red[tid] += red[tid + st];
        __syncthreads();
    }
    if (tid == 0) {
        out[LH_OFF] = (float)(lh / 256.0);
        out[KL_OFF] = (float)(red[0] / 2048.0);
    }
}

extern "C" void kernel_launch(void* const* d_in, const int* in_sizes, int n_in,
                              void* d_out, int out_size, void* d_ws, size_t ws_size,
                              hipStream_t stream) {
    const float* X     = (const float*)d_in[0];
    const float* eps   = (const float*)d_in[1];
    const float* ew1   = (const float*)d_in[2];
    const float* eb1   = (const float*)d_in[3];
    const float* ew2   = (const float*)d_in[4];
    const float* eb2   = (const float*)d_in[5];
    const float* ew3   = (const float*)d_in[6];
    const float* eb3   = (const float*)d_in[7];
    const float* fc1w  = (const float*)d_in[8];
    const float* fc1b  = (const float*)d_in[9];
    const float* fc2w  = (const float*)d_in[10];
    const float* fc2b  = (const float*)d_in[11];
    const float* fw1   = (const float*)d_in[12];
    const float* fb1   = (const float*)d_in[13];
    const float* fw2   = (const float*)d_in[14];
    const float* fb2   = (const float*)d_in[15];
    const float* fw3   = (const float*)d_in[16];
    const float* fb3   = (const float*)d_in[17];
    const float* fc3w  = (const float*)d_in[18];
    const float* fc3b  = (const float*)d_in[19];
    const float* dw1   = (const float*)d_in[20];
    const float* db1   = (const float*)d_in[21];
    const float* dw2   = (const float*)d_in[22];
    const float* db2   = (const float*)d_in[23];
    const float* dw3   = (const float*)d_in[24];
    const float* db3   = (const float*)d_in[25];

    float* out = (float*)d_out;
    char* ws = (char*)d_ws;
    float* lhp = (float*)ws;
    float* klp = (float*)(ws + 12800);
    float* z0  = (float*)(ws + 13824);
    float* M1p = (float*)(ws + 22016);
    unsigned int* Wp2 = (unsigned int*)(ws + 59648);
    float* Wc3 = (float*)(ws + 72448);

    prep_kernel<<<51, 256, 0, stream>>>(fc3w, fc3b, dw1, db1, dw2, dw3, M1p, Wp2, Wc3);
    enc_kernel<<<256, 256, 0, stream>>>(X, eps, ew1, eb1, ew2, eb2, ew3, eb3,
                                        fc1w, fc1b, fc2w, fc2b, out, z0, klp);
    ode_kernel<<<256, 256, 0, stream>>>(z0, fw1, fb1, fw2, fb2, fw3, fb3, out + ZT_OFF);
    dec_kernel<<<3200, 256, 0, stream>>>(M1p, out + ZT_OFF, Wp2, db2, Wc3, db3,
                                         X, out + XREC_OFF, lhp);
    fin_kernel<<<1, 256, 0, stream>>>(lhp, klp, out);
}

// Round 7
// 408.065 us; speedup vs baseline: 1.4794x; 1.0227x over previous
//
#include <hip/hip_runtime.h>
#include <math.h>

#define DT 0.1f
#define EPSL 1e-5f

// ---- output layout (float32, concatenated in reference return order) ----
#define XREC_OFF 0
#define QM_OFF   10035200
#define QV_OFF   10037248
#define ZT_OFF   10039296
#define LH_OFF   10141696
#define KL_OFF   10141697

// ---- workspace layout (bytes) ----
// lhp  float[3200]   @ 0
// klp  float[256]    @ 12800
// (z0 region unused since R7 merge)
// M1p  float[784*12] @ 22016
// Wp2  u32[1600]     @ 59648   (bf16-paired convT2 weights)
// Wc3p u32[100]      @ 72448   (bf16-paired convT3 weights)

__device__ __forceinline__ unsigned short f2bf(float x) {
    unsigned int u = __float_as_uint(x);
    u += 0x7fffu + ((u >> 16) & 1u);
    return (unsigned short)(u >> 16);
}
__device__ __forceinline__ unsigned int pk2(float lo, float hi) {
    return (unsigned int)f2bf(lo) | ((unsigned int)f2bf(hi) << 16);
}
// D = S0.bf16[0]*S1.bf16[0] + S0.bf16[1]*S1.bf16[1] + S2  (exact products, f32 acc)
__device__ __forceinline__ float dot2bfs(unsigned int w, unsigned int y, float c) {
    float d;
    asm("v_dot2_f32_bf16 %0, %1, %2, %3" : "=v"(d) : "s"(w), "v"(y), "v"(c));
    return d;
}
__device__ __forceinline__ float rl(float v, int lane) {
    return __uint_as_float(__builtin_amdgcn_readlane(__float_as_uint(v), lane));
}

// =====================================================================
// Front kernel: prep-slice + encoder + ODE, one block per sample.
//  - prep spread across all 256 blocks (thread tid<51 does item
//    tid*256+n): every block pays ~one-item latency instead of the
//    stream paying prep's whole wall time serially.
//  - enc v3 (bit-exact), z passed to ODE via LDS (no global roundtrip).
//  - ODE v4 body (known 117 us).
// =====================================================================
__global__ __launch_bounds__(256, 1) void front_kernel(
    const float* __restrict__ X, const float* __restrict__ eps,
    const float* __restrict__ w1, const float* __restrict__ b1,
    const float* __restrict__ w2, const float* __restrict__ b2,
    const float* __restrict__ w3, const float* __restrict__ b3,
    const float* __restrict__ fc1w, const float* __restrict__ fc1b,
    const float* __restrict__ fc2w, const float* __restrict__ fc2b,
    const float* __restrict__ fw1, const float* __restrict__ fb1,
    const float* __restrict__ fw2, const float* __restrict__ fb2,
    const float* __restrict__ fw3, const float* __restrict__ fb3,
    const float* __restrict__ fc3w, const float* __restrict__ fc3b,
    const float* __restrict__ dw1, const float* __restrict__ db1,
    const float* __restrict__ dw2, const float* __restrict__ dw3,
    float* __restrict__ out, float* __restrict__ klp,
    float* __restrict__ M1p, unsigned int* __restrict__ Wp2,
    unsigned int* __restrict__ Wc3p)
{
    __shared__ float imgp[33][33];
    __shared__ float a1p[8][17][17];
    __shared__ float a2p[16][11][11];
    __shared__ float h[512];
    __shared__ float w1s[200];
    __shared__ float w2s[3200];
    __shared__ float w3s[12800];
    __shared__ float fcred[16];
    __shared__ float kl_s[8];
    __shared__ float zsh[8];
    __shared__ float part2[4][104];
    __shared__ float part3[4][8];
    int n = blockIdx.x, tid = threadIdx.x;

    // ---------------- prep slice (threads 0..50, one item each) ----------
    if (tid < 51) {
        int idx = tid * 256 + n;
        if (idx < 9408) {                       // M1p [784][12]
            int m = idx / 12, j = idx % 12;
            float acc = 0.f;
            if (j < 9) {
                int oc = m / 49, r = m % 49, oy = r / 7, ox = r % 7;
                acc = (j == 8) ? db1[oc] : 0.f;
                for (int ky = 0; ky < 5; ++ky) {
                    int ty = oy + ky - 2;
                    if (ty < 0 || (ty & 1)) continue;
                    int iy = ty >> 1; if (iy >= 4) continue;
                    for (int kx = 0; kx < 5; ++kx) {
                        int tx = ox + kx - 2;
                        if (tx < 0 || (tx & 1)) continue;
                        int ix = tx >> 1; if (ix >= 4) continue;
                        for (int ic = 0; ic < 32; ++ic) {
                            float wv = dw1[((oc * 32 + ic) * 5 + ky) * 5 + kx];
                            int mi = ic * 16 + iy * 4 + ix;
                            acc += wv * ((j < 8) ? fc3w[mi * 8 + j] : fc3b[mi]);
                        }
                    }
                }
            }
            M1p[idx] = acc;
        } else if (idx < 9408 + 3200) {         // Wp2 repack, dw2 [8][16][5][5]
            int iw = idx - 9408;
            int kx = iw % 5, t1 = iw / 5, ky = t1 % 5, t2 = t1 / 5, ic = t2 % 16, oc = t2 / 16;
            int cy = ky & 1, cx = kx & 1, dy = ky >> 1, dx = kx >> 1;
            int ny = cy ? 2 : 3, nx = cx ? 2 : 3, nt = ny * nx;
            const int off2[4] = {0, 576, 960, 1344};   // u32-pair units
            int icp = ic >> 1, half = ic & 1;
            unsigned short* Wp2h = (unsigned short*)Wp2;
            Wp2h[(off2[cy * 2 + cx] + (icp * 8 + oc) * nt + dy * nx + dx) * 2 + half] = f2bf(dw2[iw]);
        } else if (idx < 9408 + 3200 + 200) {   // Wc3 repack (bf16 ic-pairs)
            int iw = idx - 12608;
            int kx = iw % 5, t1 = iw / 5, ky = t1 % 5, ic = t1 / 5;
            int cy = ky & 1, cx = kx & 1, dy = ky >> 1, dx = kx >> 1;
            int ny = cy ? 2 : 3, nx = cx ? 2 : 3, nt = ny * nx;
            const int off3[4] = {0, 36, 60, 84};       // u32-pair units
            int icp = ic >> 1, half = ic & 1;
            unsigned short* Wc3h = (unsigned short*)Wc3p;
            Wc3h[(off3[cy * 2 + cx] + icp * nt + dy * nx + dx) * 2 + half] = f2bf(dw3[iw]);
        }
    }

    // ---------------- encoder (v3, bit-exact) ----------------------------
    for (int i = tid; i < 1089; i += 256) ((float*)imgp)[i] = 0.f;
    for (int i = tid; i < 2312; i += 256) ((float*)a1p)[i] = 0.f;
    for (int i = tid; i < 1936; i += 256) ((float*)a2p)[i] = 0.f;
    for (int i = tid; i < 50;   i += 256) ((float4*)w1s)[i] = ((const float4*)w1)[i];
    for (int i = tid; i < 800;  i += 256) ((float4*)w2s)[i] = ((const float4*)w2)[i];
    for (int i = tid; i < 3200; i += 256) ((float4*)w3s)[i] = ((const float4*)w3)[i];
    __syncthreads();

    const float* xi = X + (size_t)n * 39200;
    for (int i = tid; i < 784; i += 256) imgp[2 + i / 28][2 + i % 28] = xi[i];
    __syncthreads();

    {
        int oc = tid >> 5, p0 = tid & 31;
        float wr[25];
        #pragma unroll
        for (int q = 0; q < 25; ++q) wr[q] = w1s[oc * 25 + q];
        float bb = b1[oc];
        #pragma unroll 1
        for (int k = 0; k < 7; ++k) {
            int px = p0 + 32 * k;
            if (px < 196) {
                int oy = px / 14, ox = px % 14;
                float acc = bb;
                #pragma unroll
                for (int ky = 0; ky < 5; ++ky)
                    #pragma unroll
                    for (int kx = 0; kx < 5; ++kx)
                        acc = fmaf(wr[ky * 5 + kx], imgp[2 * oy + ky][2 * ox + kx], acc);
                a1p[oc][2 + oy][2 + ox] = fmaxf(acc, 0.f);
            }
        }
    }
    __syncthreads();

    {
        int oc = tid >> 4, p0 = tid & 15;
        float bb = b2[oc];
        float acc[4] = {bb, bb, bb, bb};
        #pragma unroll 1
        for (int ic = 0; ic < 8; ++ic) {
            float wr[25];
            #pragma unroll
            for (int q = 0; q < 25; ++q) wr[q] = w2s[(oc * 8 + ic) * 25 + q];
            #pragma unroll
            for (int k = 0; k < 4; ++k) {
                int px = p0 + 16 * k;
                if (px < 49) {
                    int oy = px / 7, ox = px % 7;
                    #pragma unroll
                    for (int ky = 0; ky < 5; ++ky)
                        #pragma unroll
                        for (int kx = 0; kx < 5; ++kx)
                            acc[k] = fmaf(wr[ky * 5 + kx], a1p[ic][2 * oy + ky][2 * ox + kx], acc[k]);
                }
            }
        }
        #pragma unroll
        for (int k = 0; k < 4; ++k) {
            int px = p0 + 16 * k;
            if (px < 49) {
                int oy = px / 7, ox = px % 7;
                a2p[oc][2 + oy][2 + ox] = fmaxf(acc[k], 0.f);
            }
        }
    }
    __syncthreads();

    {
        int oc = tid >> 3, p0 = tid & 7;
        float bb = b3[oc];
        float acc[2] = {bb, bb};
        #pragma unroll 1
        for (int ic = 0; ic < 16; ++ic) {
            float wr[25];
            #pragma unroll
            for (int q = 0; q < 25; ++q) wr[q] = w3s[(oc * 16 + ic) * 25 + q];
            #pragma unroll
            for (int k = 0; k < 2; ++k) {
                int px = p0 + 8 * k;
                int oy = px >> 2, ox = px & 3;
                #pragma unroll
                for (int ky = 0; ky < 5; ++ky)
                    #pragma unroll
                    for (int kx = 0; kx < 5; ++kx)
                        acc[k] = fmaf(wr[ky * 5 + kx], a2p[ic][2 * oy + ky][2 * ox + kx], acc[k]);
            }
        }
        #pragma unroll
        for (int k = 0; k < 2; ++k) {
            int px = p0 + 8 * k;
            h[oc * 16 + px] = fmaxf(acc[k], 0.f);
        }
    }
    __syncthreads();

    if (tid < 128) {
        int wv = tid >> 6, L = tid & 63, o = L >> 3, rr = L & 7;
        const float* fw = (wv ? fc2w : fc1w) + o * 512;
        float p = 0.f;
        #pragma unroll 8
        for (int j = 0; j < 64; ++j) {
            int k = rr + 8 * j;
            p = fmaf(fw[k], h[k], p);
        }
        p += __shfl_down(p, 4, 8);
        p += __shfl_down(p, 2, 8);
        p += __shfl_down(p, 1, 8);
        if (rr == 0) fcred[wv * 8 + o] = p;
    }
    __syncthreads();
    if (tid < 8) {
        float m = fc1b[tid] + fcred[tid];
        float lv = fc2b[tid] + fcred[8 + tid];
        float v = fmaxf(lv, 0.f) + log1pf(expf(-fabsf(lv)));
        float z = m + eps[n * 8 + tid] * v;
        out[QM_OFF + n * 8 + tid] = m;
        out[QV_OFF + n * 8 + tid] = v;
        zsh[tid] = z;
        kl_s[tid] = -logf(v) + 0.5f * (v * v + m * m) - 0.5f;
    }
    __syncthreads();
    if (tid == 0) {
        float s = 0.f;
        for (int i = 0; i < 8; ++i) s += kl_s[i];
        klp[n] = s;
    }

    // ---------------- ODE (v4 body, z from LDS) --------------------------
    {
        float* ztg = out + ZT_OFF;
        int w = tid >> 6, L = tid & 63;
        int i3 = L & 7;
        bool act25 = (L < 25);
        int j1 = 25 * w + L;
        bool hiv = (L < 36);
        int jA = L, jB = L + 64;
        int k0 = 25 * w;

        float w1r[8];
        float b1A = 0.f, b2A = 0.f;
        if (act25) {
            b1A = fb1[j1];
            b2A = fb2[j1];
            #pragma unroll
            for (int k = 0; k < 8; ++k) w1r[k] = fw1[j1 * 8 + k];
        } else {
            #pragma unroll
            for (int k = 0; k < 8; ++k) w1r[k] = 0.f;
        }
        float w2x[25], w2y[25], w3r[25];
        #pragma unroll
        for (int kk = 0; kk < 25; ++kk) {
            w2x[kk] = fw2[jA * 100 + k0 + kk];
            w2y[kk] = hiv ? fw2[jB * 100 + k0 + kk] : 0.f;
            w3r[kk] = fw3[i3 * 100 + k0 + kk];
        }
        float b3r = fb3[i3];

        float zc = zsh[i3];
        if (tid < 8) ztg[n * 400 + tid] = zc;
        float vu[8];
        #pragma unroll
        for (int i = 0; i < 8; ++i) vu[i] = rl(zc, i);

        #pragma unroll 1
        for (int t = 1; t < 50; ++t) {
            float zsum = 0.f;
            #pragma unroll 1
            for (int st = 0; st < 4; ++st) {
                float aA = 0.f;
                if (act25) {
                    float a = b1A;
                    #pragma unroll
                    for (int k = 0; k < 8; ++k) a = fmaf(w1r[k], vu[k], a);
                    aA = fmaxf(a, 0.f);
                }

                float ha[4] = {0.f, 0.f, 0.f, 0.f};
                float hb[4] = {0.f, 0.f, 0.f, 0.f};
                #pragma unroll
                for (int kk = 0; kk < 25; ++kk) {
                    float s = rl(aA, kk);
                    ha[kk & 3] = fmaf(w2x[kk], s, ha[kk & 3]);
                    hb[kk & 3] = fmaf(w2y[kk], s, hb[kk & 3]);
                }
                part2[w][L] = (ha[0] + ha[1]) + (ha[2] + ha[3]);
                if (hiv) part2[w][64 + L] = (hb[0] + hb[1]) + (hb[2] + hb[3]);
                __syncthreads();

                float h2v = 0.f;
                if (act25) {
                    float sA = (part2[0][j1] + part2[1][j1]) + (part2[2][j1] + part2[3][j1]);
                    h2v = fmaxf(b2A + sA, 0.f);
                }

                float oa[4] = {0.f, 0.f, 0.f, 0.f};
                #pragma unroll
                for (int kk = 0; kk < 25; ++kk) {
                    float s = rl(h2v, kk);
                    oa[kk & 3] = fmaf(w3r[kk], s, oa[kk & 3]);
                }
                if (L < 8) part3[w][L] = (oa[0] + oa[1]) + (oa[2] + oa[3]);
                __syncthreads();

                float o = b3r + ((part3[0][i3] + part3[1][i3]) + (part3[2][i3] + part3[3][i3]));
                float cw = (st == 0 || st == 3) ? (DT / 6.f) : (DT / 3.f);
                zsum = fmaf(cw, o, zsum);
                float vn;
                if (st < 3) {
                    float cin = (st == 2) ? DT : 0.5f * DT;
                    vn = fmaf(cin, o, zc);
                } else {
                    zc = zc + zsum;
                    vn = zc;
                    if (tid < 8) ztg[n * 400 + t * 8 + tid] = zc;
                }
                #pragma unroll
                for (int i = 0; i < 8; ++i) vu[i] = rl(vn, i);
            }
        }
    }
}

// =====================================================================
// Decoder v10: dot2 phase 1 AND phase 2 (Wc3 bf16 ic-paired).
// =====================================================================
__global__ __launch_bounds__(256, 5) void dec_kernel(
    const float* __restrict__ M1p, const float* __restrict__ zt,
    const unsigned int* __restrict__ Wp2, const float* __restrict__ db2,
    const unsigned int* __restrict__ Wc3p, const float* __restrict__ db3,
    const float* __restrict__ X, float* __restrict__ xrec,
    float* __restrict__ lhp)
{
    __shared__ __align__(16) unsigned int y1p[4][8][9][10];    // bf16 ic-pairs, 11520 B
    __shared__ __align__(16) unsigned int y2p[4][4][16][17];   // bf16 ic-pairs, 17408 B
    __shared__ float red4[4];
    int blk = blockIdx.x, tid = threadIdx.x;
    int wv = tid >> 6, L = tid & 63;

    {
        uint4 z4 = uint4{0u, 0u, 0u, 0u};
        for (int i = tid; i < 720;  i += 256) ((uint4*)y1p)[i] = z4;
        for (int i = tid; i < 1088; i += 256) ((uint4*)y2p)[i] = z4;
    }
    __syncthreads();

    // phase 0: y1 = relu(M1 @ z + b), two channels (one pair) per work item
    {
        float zr[4][8];
        const float* zp = zt + (size_t)blk * 32;
        #pragma unroll
        for (int s = 0; s < 4; ++s)
            #pragma unroll
            for (int jj = 0; jj < 8; ++jj) zr[s][jj] = zp[s * 8 + jj];
        for (int m2 = tid; m2 < 392; m2 += 256) {
            int icp = m2 / 49, r = m2 % 49, oy = r / 7, ox = r % 7;
            const float4* rowA = (const float4*)(M1p + (size_t)((icp * 2) * 49 + r) * 12);
            const float4* rowB = (const float4*)(M1p + (size_t)((icp * 2 + 1) * 49 + r) * 12);
            float4 a0 = rowA[0], a1 = rowA[1], a2 = rowA[2];
            float4 b0 = rowB[0], b1 = rowB[1], b2 = rowB[2];
            #pragma unroll
            for (int s = 0; s < 4; ++s) {
                float aA = a2.x
                    + a0.x * zr[s][0] + a0.y * zr[s][1] + a0.z * zr[s][2] + a0.w * zr[s][3]
                    + a1.x * zr[s][4] + a1.y * zr[s][5] + a1.z * zr[s][6] + a1.w * zr[s][7];
                float aB = b2.x
                    + b0.x * zr[s][0] + b0.y * zr[s][1] + b0.z * zr[s][2] + b0.w * zr[s][3]
                    + b1.x * zr[s][4] + b1.y * zr[s][5] + b1.z * zr[s][6] + b1.w * zr[s][7];
                y1p[s][icp][1 + oy][1 + ox] = pk2(fmaxf(aA, 0.f), fmaxf(aB, 0.f));
            }
        }
    }
    __syncthreads();

    // phase 1: convT2 fused 4-class 2x2 tiles via v_dot2_f32_bf16.
    {
        int pos = (L < 49) ? L : 48;
        int s = wv, m = pos / 7, n = pos % 7;
        float acc[4][8];
        #pragma unroll
        for (int oc = 0; oc < 8; ++oc) {
            float b = db2[oc];
            acc[0][oc] = b; acc[1][oc] = b; acc[2][oc] = b; acc[3][oc] = b;
        }
        #pragma unroll 2
        for (int icp = 0; icp < 8; ++icp) {
            unsigned int yv[3][3];
            #pragma unroll
            for (int ry = 0; ry < 3; ++ry)
                #pragma unroll
                for (int rx = 0; rx < 3; ++rx)
                    yv[ry][rx] = y1p[s][icp][m + ry][n + rx];
            #pragma unroll
            for (int oc = 0; oc < 8; ++oc) {
                const unsigned int* p00 = Wp2 + (icp * 8 + oc) * 9;
                const unsigned int* p01 = Wp2 + 576 + (icp * 8 + oc) * 6;
                const unsigned int* p10 = Wp2 + 960 + (icp * 8 + oc) * 6;
                const unsigned int* p11 = Wp2 + 1344 + (icp * 8 + oc) * 4;
                #pragma unroll
                for (int dy = 0; dy < 3; ++dy)
                    #pragma unroll
                    for (int dx = 0; dx < 3; ++dx)
                        acc[0][oc] = dot2bfs(p00[dy * 3 + dx], yv[dy][dx], acc[0][oc]);
                #pragma unroll
                for (int dy = 0; dy < 3; ++dy)
                    #pragma unroll
                    for (int dx = 0; dx < 2; ++dx)
                        acc[1][oc] = dot2bfs(p01[dy * 2 + dx], yv[dy][dx + 1], acc[1][oc]);
                #pragma unroll
                for (int dy = 0; dy < 2; ++dy)
                    #pragma unroll
                    for (int dx = 0; dx < 3; ++dx)
                        acc[2][oc] = dot2bfs(p10[dy * 3 + dx], yv[dy + 1][dx], acc[2][oc]);
                #pragma unroll
                for (int dy = 0; dy < 2; ++dy)
                    #pragma unroll
                    for (int dx = 0; dx < 2; ++dx)
                        acc[3][oc] = dot2bfs(p11[dy * 2 + dx], yv[dy + 1][dx + 1], acc[3][oc]);
            }
        }
        if (L < 49) {
            #pragma unroll
            for (int p = 0; p < 4; ++p) {
                y2p[s][p][1 + 2 * m][1 + 2 * n] = pk2(fmaxf(acc[0][2 * p], 0.f), fmaxf(acc[0][2 * p + 1], 0.f));
                y2p[s][p][1 + 2 * m][2 + 2 * n] = pk2(fmaxf(acc[1][2 * p], 0.f), fmaxf(acc[1][2 * p + 1], 0.f));
                y2p[s][p][2 + 2 * m][1 + 2 * n] = pk2(fmaxf(acc[2][2 * p], 0.f), fmaxf(acc[2][2 * p + 1], 0.f));
                y2p[s][p][2 + 2 * m][2 + 2 * n] = pk2(fmaxf(acc[3][2 * p], 0.f), fmaxf(acc[3][2 * p + 1], 0.f));
            }
        }
    }
    __syncthreads();

    // phase 2: convT3 fused 4-class 2x2 tiles via dot2 + sigmoid + lhood
    float part = 0.f;
    {
        float b3v = db3[0];
        const unsigned int* q00 = Wc3p;         // 4 icp x 9
        const unsigned int* q01 = Wc3p + 36;    // 4 icp x 6
        const unsigned int* q10 = Wc3p + 60;    // 4 icp x 6
        const unsigned int* q11 = Wc3p + 84;    // 4 icp x 4
        #pragma unroll 1
        for (int ch = 0; ch < 4; ++ch) {
            int g = ch * 256 + tid;
            if (g < 784) {
                int s2 = g / 196, r2 = g % 196, m = r2 / 14, n = r2 % 14;
                float o00 = b3v, o01 = b3v, o10 = b3v, o11 = b3v;
                #pragma unroll
                for (int icp = 0; icp < 4; ++icp) {
                    unsigned int yv[3][3];
                    #pragma unroll
                    for (int ry = 0; ry < 3; ++ry)
                        #pragma unroll
                        for (int rx = 0; rx < 3; ++rx)
                            yv[ry][rx] = y2p[s2][icp][m + ry][n + rx];
                    #pragma unroll
                    for (int dy = 0; dy < 3; ++dy)
                        #pragma unroll
                        for (int dx = 0; dx < 3; ++dx)
                            o00 = dot2bfs(q00[icp * 9 + dy * 3 + dx], yv[dy][dx], o00);
                    #pragma unroll
                    for (int dy = 0; dy < 3; ++dy)
                        #pragma unroll
                        for (int dx = 0; dx < 2; ++dx)
                            o01 = dot2bfs(q01[icp * 6 + dy * 2 + dx], yv[dy][dx + 1], o01);
                    #pragma unroll
                    for (int dy = 0; dy < 2; ++dy)
                        #pragma unroll
                        for (int dx = 0; dx < 3; ++dx)
                            o10 = dot2bfs(q10[icp * 6 + dy * 3 + dx], yv[dy + 1][dx], o10);
                    #pragma unroll
                    for (int dy = 0; dy < 2; ++dy)
                        #pragma unroll
                        for (int dx = 0; dx < 2; ++dx)
                            o11 = dot2bfs(q11[icp * 4 + dy * 2 + dx], yv[dy + 1][dx + 1], o11);
                }
                float p00s = 1.f / (1.f + __expf(-o00));
                float p01s = 1.f / (1.f + __expf(-o01));
                float p10s = 1.f / (1.f + __expf(-o10));
                float p11s = 1.f / (1.f + __expf(-o11));
                size_t base = (size_t)blk * 3136 + s2 * 784 + 2 * m * 28 + 2 * n;
                *(float2*)(xrec + base)      = float2{p00s, p01s};
                *(float2*)(xrec + base + 28) = float2{p10s, p11s};
                float2 x0 = *(const float2*)(X + base);
                float2 x1 = *(const float2*)(X + base + 28);
                part += __logf(EPSL + p00s) * x0.x + __logf(EPSL + 1.f - p00s) * (1.f - x0.x);
                part += __logf(EPSL + p01s) * x0.y + __logf(EPSL + 1.f - p01s) * (1.f - x0.y);
                part += __logf(EPSL + p10s) * x1.x + __logf(EPSL + 1.f - p10s) * (1.f - x1.x);
                part += __logf(EPSL + p11s) * x1.y + __logf(EPSL + 1.f - p11s) * (1.f - x1.y);
            }
        }
    }
    // per-wave shuffle reduce, then one cross-wave combine
    part += __shfl_down(part, 32);
    part += __shfl_down(part, 16);
    part += __shfl_down(part, 8);
    part += __shfl_down(part, 4);
    part += __shfl_down(part, 2);
    part += __shfl_down(part, 1);
    if (L == 0) red4[wv] = part;
    __syncthreads();
    if (tid == 0) lhp[blk] = (red4[0] + red4[1]) + (red4[2] + red4[3]);
}

// =====================================================================
// Finalize
// =====================================================================
__global__ __launch_bounds__(256) void fin_kernel(
    const float* __restrict__ lhp, const float* __restrict__ klp,
    float* __restrict__ out)
{
    __shared__ double red[256];
    int tid = threadIdx.x;
    double s = 0.0;
    for (int i = tid; i < 3200; i += 256) s += (double)lhp[i];
    red[tid] = s;
    __syncthreads();
    for (int st = 128; st > 0; st >>= 1) {
        if (tid < st) red[tid] += red[tid + st];
        __syncthreads();
    }
    double lh = red[0];
    __syncthreads();
    red[tid] = (double)klp[tid];
    __syncthreads();
    for (int st = 128; st > 0; st >>= 1) {
        if (tid < st) red[tid] += red[tid + st];
        __syncthreads();
    }
    if (tid == 0) {
        out[LH_OFF] = (float)(lh / 256.0);
        out[KL_OFF] = (float)(red[0] / 2048.0);
    }
}

extern "C" void kernel_launch(void* const* d_in, const int* in_sizes, int n_in,
                              void* d_out, int out_size, void* d_ws, size_t ws_size,
                              hipStream_t stream) {
    const float* X     = (const float*)d_in[0];
    const float* eps   = (const float*)d_in[1];
    const float* ew1   = (const float*)d_in[2];
    const float* eb1   = (const float*)d_in[3];
    const float* ew2   = (const float*)d_in[4];
    const float* eb2   = (const float*)d_in[5];
    const float* ew3   = (const float*)d_in[6];
    const float* eb3   = (const float*)d_in[7];
    const float* fc1w  = (const float*)d_in[8];
    const float* fc1b  = (const float*)d_in[9];
    const float* fc2w  = (const float*)d_in[10];
    const float* fc2b  = (const float*)d_in[11];
    const float* fw1   = (const float*)d_in[12];
    const float* fb1   = (const float*)d_in[13];
    const float* fw2   = (const float*)d_in[14];
    const float* fb2   = (const float*)d_in[15];
    const float* fw3   = (const float*)d_in[16];
    const float* fb3   = (const float*)d_in[17];
    const float* fc3w  = (const float*)d_in[18];
    const float* fc3b  = (const float*)d_in[19];
    const float* dw1   = (const float*)d_in[20];
    const float* db1   = (const float*)d_in[21];
    const float* dw2   = (const float*)d_in[22];
    const float* db2   = (const float*)d_in[23];
    const float* dw3   = (const float*)d_in[24];
    const float* db3   = (const float*)d_in[25];

    float* out = (float*)d_out;
    char* ws = (char*)d_ws;
    float* lhp = (float*)ws;
    float* klp = (float*)(ws + 12800);
    float* M1p = (float*)(ws + 22016);
    unsigned int* Wp2  = (unsigned int*)(ws + 59648);
    unsigned int* Wc3p = (unsigned int*)(ws + 72448);

    front_kernel<<<256, 256, 0, stream>>>(X, eps, ew1, eb1, ew2, eb2, ew3, eb3,
                                          fc1w, fc1b, fc2w, fc2b,
                                          fw1, fb1, fw2, fb2, fw3, fb3,
                                          fc3w, fc3b, dw1, db1, dw2, dw3,
                                          out, klp, M1p, Wp2, Wc3p);
    dec_kernel<<<3200, 256, 0, stream>>>(M1p, out + ZT_OFF, Wp2, db2, Wc3p, db3,
                                         X, out + XREC_OFF, lhp);
    fin_kernel<<<1, 256, 0, stream>>>(lhp, klp, out);
}